// Round 5
// baseline (1703.638 us; speedup 1.0000x reference)
//
#include <hip/hip_runtime.h>

// ---------------------------------------------------------------------------
// CriticNetwork: GRU over T=256 steps (B=1024, H=256, F=65) + 2-critic MLP.
// Kernel 1 (gru_kernel): persistent, 256 blocks x 1024 thr (16 waves,
//   4 waves/SIMD). Round-4 lesson: masked ds_reads + manual 2-deep pipeline
//   + setprio = +1700 cy/step of stalls (defeats compiler lgkmcnt schedule;
//   setprio null in lockstep) -> all reverted to round-3 pattern.
//   THIS ROUND: 16 waves, each owning ONE hidden-col group with all 3 gates
//   (N-tiles {w, w+16, w+32}); whb = 3x8 fragments = 96 regs/wave ->
//   fits 4 waves/SIMD (<=256 regs/wave) -> 2x occupancy, TLP hides the
//   serial ds_read->MFMA->gate->barrier chain. Per-SIMD MFMA/step unchanged
//   (4 waves x 24 = 96). Kept from r4: xp in 12 packed bf16 regs, C-init
//   folding (bi+wv*w64 as xp C-in; xp/bhn as recurrence C-in).
// Kernel 2 (head_kernel): twin critic MLPs, 64 blocks x 32 rows (kept).
// ---------------------------------------------------------------------------

#define TSEQ 256
#define DPDIM 64

typedef float f32x4 __attribute__((ext_vector_type(4)));
typedef __bf16 bf16x8 __attribute__((ext_vector_type(8)));
typedef unsigned short ushort8 __attribute__((ext_vector_type(8)));

static __device__ __forceinline__ unsigned short f2bf(float f) {
  unsigned u = __builtin_bit_cast(unsigned, f);
  return (unsigned short)((u + 0x7fffu + ((u >> 16) & 1u)) >> 16);  // RNE
}
static __device__ __forceinline__ float bf2f(unsigned short h) {
  return __builtin_bit_cast(float, ((unsigned)h) << 16);
}
static __device__ __forceinline__ unsigned pk2(float a, float b) {  // RNE pack
  return (unsigned)f2bf(a) | ((unsigned)f2bf(b) << 16);
}
// static tt in [0,4): select bf16 half of uint2, expand to f32 (1 bit-op)
static __device__ __forceinline__ float upk(uint2 v, int tt) {
  unsigned u = (tt & 2) ? v.y : v.x;
  return (tt & 1) ? __builtin_bit_cast(float, u & 0xffff0000u)
                  : __builtin_bit_cast(float, u << 16);
}
static __device__ __forceinline__ float sigm(float x) {
  return __builtin_amdgcn_rcpf(1.f + __expf(-x));
}
static __device__ __forceinline__ float tanh_fast(float p) {
  float q = __expf(-2.f * fabsf(p));
  float t = (1.f - q) * __builtin_amdgcn_rcpf(1.f + q);
  return __builtin_bit_cast(float, __builtin_bit_cast(unsigned, t) |
                                   (__builtin_bit_cast(unsigned, p) & 0x80000000u));
}

// ---- GRU kernel LDS layout (bytes) ----
#define OFF_WIT 0         // Wi transposed bf16 [768 n][72 k-stride] = 768*144
#define OFF_H0  110592    // h buf0 bf16 [4 real rows + 1 zero row][272] stride 544B
#define OFF_H1  113312    // h buf1
#define OFF_BI  116032    // bi f32 [768]
#define OFF_W64 119104    // Wi row 64 (weight channel) f32 [768]
#define LDS_GRU 122176

#define HSTRIDE 544       // h row stride (rows land on banks {0,8,16,24})

__global__ __launch_bounds__(1024) void gru_kernel(
    const float* __restrict__ particles, const float* __restrict__ weights,
    const float* __restrict__ Wi, const float* __restrict__ bi,
    const float* __restrict__ Wh, const float* __restrict__ bhn,
    unsigned short* __restrict__ hT)
{
  extern __shared__ char smem[];
  const int tid  = threadIdx.x;
  const int lane = tid & 63;
  const int w    = tid >> 6;      // wave id 0..15
  const int l15  = lane & 15;
  const int kg   = lane >> 4;     // k-group 0..3
  const int b0   = blockIdx.x * 4;

  // ---------------- prologue ----------------
  for (int idx = tid; idx < 64 * 768; idx += 1024) {
    int k = idx / 768, n = idx - k * 768;
    *(unsigned short*)(smem + OFF_WIT + n * 144 + k * 2) = f2bf(Wi[idx]);
  }
  for (int idx = tid; idx < 768; idx += 1024) {
    *(float*)(smem + OFF_BI  + idx * 4) = bi[idx];
    *(float*)(smem + OFF_W64 + idx * 4) = Wi[64 * 768 + idx];
  }
  for (int idx = tid; idx < (2 * 5 * HSTRIDE) / 4; idx += 1024)
    ((unsigned*)(smem + OFF_H0))[idx] = 0u;   // h0 = 0 (+ shared zero row 4)

  const int hcol = w * 16 + l15;        // this lane's hidden column (0..255)
  const float bhnv = bhn[hcol];

  // Wh -> register B-fragments. Wave w owns N-tiles {w, w+16, w+32}:
  //   j=0 -> r gate, j=1 -> z gate, j=2 -> n gate (all for col group w).
  bf16x8 whb[3][8];
  #pragma unroll
  for (int j = 0; j < 3; ++j) {
    const int tile = w + 16 * j;
    const float* wp = Wh + (size_t)(kg * 8) * 768 + tile * 16 + l15;
    #pragma unroll
    for (int ks = 0; ks < 8; ++ks) {
      ushort8 tmp;
      #pragma unroll
      for (int e = 0; e < 8; ++e)
        tmp[e] = f2bf(wp[(size_t)(ks * 32 + e) * 768]);
      whb[j][ks] = __builtin_bit_cast(bf16x8, tmp);
    }
  }
  __syncthreads();

  // A-fragment source for the recurrence: M-row l15 is real iff l15%4==0
  // (batch = l15>>2, h row l15>>2); fake lanes read the shared zero row 4
  // (same-address broadcast; row bases hit banks {0,8,16,24} -> ~2-way max).
  const unsigned arow = ((l15 & 3) == 0)
                      ? (unsigned)((l15 >> 2) * HSTRIDE + kg * 16)
                      : (unsigned)(4 * HSTRIDE + kg * 16);

  // xp A-row mapping: row l15 <-> (batch=l15>>2, time=l15&3) => C reg r of
  // lane (l15,kg) = xp(batch=kg, time=t0+r).
  const float* pbase = particles +
      ((size_t)(b0 + (l15 >> 2)) * TSEQ + (l15 & 3)) * DPDIM + kg * 8;
  const float* wbase = weights + (size_t)(b0 + kg) * TSEQ;

  f32x4 acc[3];
  uint2 xpk[3];
  float hreg = 0.f;

  #pragma unroll 1
  for (int g = 0; g < 64; ++g) {
    const int t0 = g * 4;

    // ---------------- xp phase: project inputs for t0..t0+3 ----------------
    // C-init with bias + weight-channel term (replaces zero-init + fold).
    {
      f32x4 wv = *(const f32x4*)(wbase + t0);
      #pragma unroll
      for (int j = 0; j < 3; ++j) {
        const int col = hcol + 256 * j;
        const float biv  = *(const float*)(smem + OFF_BI  + col * 4);
        const float w64v = *(const float*)(smem + OFF_W64 + col * 4);
        acc[j][0] = biv + wv[0] * w64v;
        acc[j][1] = biv + wv[1] * w64v;
        acc[j][2] = biv + wv[2] * w64v;
        acc[j][3] = biv + wv[3] * w64v;
      }
    }
    #pragma unroll
    for (int ks = 0; ks < 2; ++ks) {
      const float* pp = pbase + (size_t)t0 * DPDIM + ks * 32;
      f32x4 pa = *(const f32x4*)pp;
      f32x4 pb = *(const f32x4*)(pp + 4);
      ushort8 tmp;
      tmp[0] = f2bf(pa[0]); tmp[1] = f2bf(pa[1]); tmp[2] = f2bf(pa[2]); tmp[3] = f2bf(pa[3]);
      tmp[4] = f2bf(pb[0]); tmp[5] = f2bf(pb[1]); tmp[6] = f2bf(pb[2]); tmp[7] = f2bf(pb[3]);
      bf16x8 af = __builtin_bit_cast(bf16x8, tmp);
      #pragma unroll
      for (int j = 0; j < 3; ++j) {
        const int n = hcol + 256 * j;
        bf16x8 bf = *(const bf16x8*)(smem + OFF_WIT + n * 144 + ks * 64 + kg * 16);
        acc[j] = __builtin_amdgcn_mfma_f32_16x16x32_bf16(af, bf, acc[j], 0, 0, 0);
      }
    }
    // pack xp -> 6 persistent regs (bf16 pairs; times 0..3 per gate)
    #pragma unroll
    for (int j = 0; j < 3; ++j) {
      xpk[j].x = pk2(acc[j][0], acc[j][1]);
      xpk[j].y = pk2(acc[j][2], acc[j][3]);
    }

    // ---------------- 4 GRU steps ----------------
    #pragma unroll
    for (int tt = 0; tt < 4; ++tt) {
      const int t     = t0 + tt;
      const int rboff = (t & 1) ? OFF_H1 : OFF_H0;   // read buffer
      const int wboff = (t & 1) ? OFF_H0 : OFF_H1;   // write buffer
      // C-init: r/z gates get xp; n gate gets bhn (so acc = bhn + h.Wh_n).
      acc[0][0] = upk(xpk[0], tt);
      acc[1][0] = upk(xpk[1], tt);
      acc[2][0] = bhnv;
      const char* hb = smem + rboff;
      #pragma unroll
      for (int ks = 0; ks < 8; ++ks) {
        bf16x8 af = *(const bf16x8*)(hb + arow + ks * 64);
        #pragma unroll
        for (int j = 0; j < 3; ++j)
          acc[j] = __builtin_amdgcn_mfma_f32_16x16x32_bf16(af, whb[j][ks], acc[j], 0, 0, 0);
      }
      // Gates (reg 0 = batch kg): acc[0]=xr+hp_r, acc[1]=xz+hp_z,
      // acc[2]=bhn+hp_n; xn from packed regs; previous h is hreg.
      float rr = sigm(acc[0][0]);
      float zz = sigm(acc[1][0]);
      float nn = tanh_fast(upk(xpk[2], tt) + rr * acc[2][0]);
      unsigned short hu = f2bf(nn + zz * (hreg - nn));
      hreg = bf2f(hu);
      *(unsigned short*)(smem + wboff + kg * HSTRIDE + hcol * 2) = hu;
      __syncthreads();
    }
  }

  // epilogue: final h lives in registers -> store directly
  hT[(size_t)(b0 + kg) * 256 + hcol] = f2bf(hreg);
}

// ---- Head kernel LDS layout ----
#define HOFF_XA 0         // x tile bf16 [32][296] stride 592B
#define HOFF_B  37888     // B stage bf16 [256 n][40 k] stride 80B
#define HOFF_H1 58368     // h1 bf16 [32][264] stride 528B
#define HOFF_H2 92160
#define HOFF_B1 125952
#define HOFF_B2 126976
#define HOFF_W3 128000
#define LDS_HEAD 129024

#define HROWS 32          // rows per head block (64 blocks = 32 rows x 2 critics)

__global__ __launch_bounds__(256, 2) void head_kernel(
    const unsigned short* __restrict__ hT, const float* __restrict__ action,
    const float* __restrict__ time_idx, const float* __restrict__ W1,
    const float* __restrict__ b1, const float* __restrict__ W2,
    const float* __restrict__ b2, const float* __restrict__ W3,
    const float* __restrict__ b3, float* __restrict__ out)
{
  extern __shared__ char smem[];
  const int tid  = threadIdx.x;
  const int lane = tid & 63;
  const int w    = tid >> 6;
  const int l15  = lane & 15;
  const int kg   = lane >> 4;
  const int c    = blockIdx.x & 1;
  const int rt   = blockIdx.x >> 1;
  const int r0   = rt * HROWS;

  if (tid < 256) {
    *(float*)(smem + HOFF_B1 + tid * 4) = b1[c * 256 + tid];
    *(float*)(smem + HOFF_B2 + tid * 4) = b2[c * 256 + tid];
    *(float*)(smem + HOFF_W3 + tid * 4) = W3[c * 256 + tid];
  }
  // x = [h | action | t/100 | zero-pad to 288]
  for (int idx = tid; idx < HROWS * 296; idx += 256) {
    int row = idx / 296, k = idx - row * 296;
    unsigned short v;
    if (k < 256)       v = hT[(r0 + row) * 256 + k];
    else if (k < 264)  v = f2bf(action[(r0 + row) * 8 + (k - 256)]);
    else if (k == 264) v = f2bf(time_idx[r0 + row] * 0.01f);
    else               v = 0;
    *(unsigned short*)(smem + HOFF_XA + row * 592 + k * 2) = v;
  }

  f32x4 acc[2][4];
  const f32x4 fzero = {0.f, 0.f, 0.f, 0.f};

  // ---- layer 1: h1 = relu(x @ W1[c] + b1[c]), K = 265 padded to 288 ----
  #pragma unroll
  for (int mt = 0; mt < 2; ++mt)
    #pragma unroll
    for (int i = 0; i < 4; ++i) acc[mt][i] = fzero;
  for (int ks = 0; ks < 9; ++ks) {
    for (int idx = tid; idx < 32 * 256; idx += 256) {
      int kk = idx >> 8, n = idx & 255;
      int kglob = ks * 32 + kk;
      float v = (kglob < 265) ? W1[((size_t)c * 265 + kglob) * 256 + n] : 0.f;
      *(unsigned short*)(smem + HOFF_B + n * 80 + kk * 2) = f2bf(v);
    }
    __syncthreads();
    bf16x8 bfr[4];
    #pragma unroll
    for (int i = 0; i < 4; ++i)
      bfr[i] = *(const bf16x8*)(smem + HOFF_B + ((w * 4 + i) * 16 + l15) * 80 + kg * 16);
    #pragma unroll
    for (int mt = 0; mt < 2; ++mt) {
      bf16x8 af = *(const bf16x8*)(smem + HOFF_XA + (mt * 16 + l15) * 592 + ks * 64 + kg * 16);
      #pragma unroll
      for (int i = 0; i < 4; ++i)
        acc[mt][i] = __builtin_amdgcn_mfma_f32_16x16x32_bf16(af, bfr[i], acc[mt][i], 0, 0, 0);
    }
    __syncthreads();
  }
  #pragma unroll
  for (int mt = 0; mt < 2; ++mt)
    #pragma unroll
    for (int i = 0; i < 4; ++i) {
      int col = (w * 4 + i) * 16 + l15;
      float bv = *(const float*)(smem + HOFF_B1 + col * 4);
      #pragma unroll
      for (int r = 0; r < 4; ++r) {
        float v = acc[mt][i][r] + bv; v = v > 0.f ? v : 0.f;
        *(unsigned short*)(smem + HOFF_H1 + (mt * 16 + kg * 4 + r) * 528 + col * 2) = f2bf(v);
      }
    }
  __syncthreads();

  // ---- layer 2: h2 = relu(h1 @ W2[c] + b2[c]), K = 256 ----
  #pragma unroll
  for (int mt = 0; mt < 2; ++mt)
    #pragma unroll
    for (int i = 0; i < 4; ++i) acc[mt][i] = fzero;
  for (int ks = 0; ks < 8; ++ks) {
    for (int idx = tid; idx < 32 * 256; idx += 256) {
      int kk = idx >> 8, n = idx & 255;
      float v = W2[((size_t)c * 256 + ks * 32 + kk) * 256 + n];
      *(unsigned short*)(smem + HOFF_B + n * 80 + kk * 2) = f2bf(v);
    }
    __syncthreads();
    bf16x8 bfr[4];
    #pragma unroll
    for (int i = 0; i < 4; ++i)
      bfr[i] = *(const bf16x8*)(smem + HOFF_B + ((w * 4 + i) * 16 + l15) * 80 + kg * 16);
    #pragma unroll
    for (int mt = 0; mt < 2; ++mt) {
      bf16x8 af = *(const bf16x8*)(smem + HOFF_H1 + (mt * 16 + l15) * 528 + ks * 64 + kg * 16);
      #pragma unroll
      for (int i = 0; i < 4; ++i)
        acc[mt][i] = __builtin_amdgcn_mfma_f32_16x16x32_bf16(af, bfr[i], acc[mt][i], 0, 0, 0);
    }
    __syncthreads();
  }
  #pragma unroll
  for (int mt = 0; mt < 2; ++mt)
    #pragma unroll
    for (int i = 0; i < 4; ++i) {
      int col = (w * 4 + i) * 16 + l15;
      float bv = *(const float*)(smem + HOFF_B2 + col * 4);
      #pragma unroll
      for (int r = 0; r < 4; ++r) {
        float v = acc[mt][i][r] + bv; v = v > 0.f ? v : 0.f;
        *(unsigned short*)(smem + HOFF_H2 + (mt * 16 + kg * 4 + r) * 528 + col * 2) = f2bf(v);
      }
    }
  __syncthreads();

  // ---- layer 3: v = h2 @ W3[c] + b3[c] (VALU dot, 4 threads/row) ----
  {
    int row = tid >> 2, q = tid & 3;
    if (row < HROWS) {
      float s = 0.f;
      #pragma unroll
      for (int i = 0; i < 16; ++i) {
        uint2 hh = *(const uint2*)(smem + HOFF_H2 + row * 528 + (q * 64 + i * 4) * 2);
        const float* w3p = (const float*)(smem + HOFF_W3) + q * 64 + i * 4;
        s += bf2f((unsigned short)hh.x)         * w3p[0];
        s += bf2f((unsigned short)(hh.x >> 16)) * w3p[1];
        s += bf2f((unsigned short)hh.y)         * w3p[2];
        s += bf2f((unsigned short)(hh.y >> 16)) * w3p[3];
      }
      s += __shfl_xor(s, 1);
      s += __shfl_xor(s, 2);
      if (q == 0) out[(r0 + row) * 2 + c] = s + b3[c];
    }
  }
}

extern "C" void kernel_launch(void* const* d_in, const int* in_sizes, int n_in,
                              void* d_out, int out_size, void* d_ws, size_t ws_size,
                              hipStream_t stream) {
  const float* particles = (const float*)d_in[0];
  const float* weights   = (const float*)d_in[1];
  const float* action    = (const float*)d_in[2];
  const float* time_idx  = (const float*)d_in[3];
  const float* Wi        = (const float*)d_in[4];
  const float* bi        = (const float*)d_in[5];
  const float* Wh        = (const float*)d_in[6];
  const float* bhn       = (const float*)d_in[7];
  const float* W1        = (const float*)d_in[8];
  const float* b1        = (const float*)d_in[9];
  const float* W2        = (const float*)d_in[10];
  const float* b2        = (const float*)d_in[11];
  const float* W3        = (const float*)d_in[12];
  const float* b3        = (const float*)d_in[13];
  unsigned short* hT = (unsigned short*)d_ws;   // [1024][256] bf16
  float* out = (float*)d_out;

  (void)hipFuncSetAttribute((const void*)gru_kernel,
                            hipFuncAttributeMaxDynamicSharedMemorySize, LDS_GRU);
  (void)hipFuncSetAttribute((const void*)head_kernel,
                            hipFuncAttributeMaxDynamicSharedMemorySize, LDS_HEAD);

  hipLaunchKernelGGL(gru_kernel, dim3(256), dim3(1024), LDS_GRU, stream,
                     particles, weights, Wi, bi, Wh, bhn, hT);
  hipLaunchKernelGGL(head_kernel, dim3(64), dim3(256), LDS_HEAD, stream,
                     hT, action, time_idx, W1, b1, W2, b2, W3, b3, out);
}

// Round 6
// 1636.206 us; speedup vs baseline: 1.0412x; 1.0412x over previous
//
#include <hip/hip_runtime.h>

// ---------------------------------------------------------------------------
// CriticNetwork: GRU over T=256 steps (B=1024, H=256, F=65) + 2-critic MLP.
// Kernel 1 (gru_kernel): persistent, 256 blocks x 512 thr (8 waves, 2/SIMD).
//   OCCUPANCY WALL (r5 lesson): register-resident Wh = 384 KB/CU of regfile
//   regardless of wave split; CU file = 512 KB -> 2 waves/SIMD is the max.
//   1024-thr attempt spilled 4.7 GB. Do not retry without removing Wh from
//   registers (impossible: LDS too small).
//   Structure (r3 skeleton + r4's good parts, r4's bad bundle reverted):
//   - Wh bf16 B-fragments in regs (whb[6][8], wave w owns N-tiles {w+8j}).
//   - xp M-row mapping row<->(batch=row>>2, time=row&3): lane (l15,kg) reg r
//     = xp(batch=kg,time=t0+r) -> xp lives in 12 packed bf16 regs (uint2 x6),
//     no LDS slot, no shuffles (r4-proven: conflicts 3.5e7 -> 7.5e6).
//   - C-init folding: xp-phase C-in = bi + wv*w64; recurrence C-in = xp (r,z)
//     / bhn (n) -> no zero-init, no separate fold pass.
//   - Plain 8x ds_read_b128 ks-loop, compiler-scheduled (r4 lesson: manual
//     2-deep pipeline / masked loads / setprio = +1700 cy/step. Never again).
//   - h in a register per lane; LDS h write only for other waves' A-reads;
//     fake A-lanes broadcast-read shared zero row 4 (5-row buf, stride 544).
// Kernel 2 (head_kernel): twin critic MLPs, 64 blocks x 32 rows.
// ---------------------------------------------------------------------------

#define TSEQ 256
#define DPDIM 64

typedef float f32x4 __attribute__((ext_vector_type(4)));
typedef __bf16 bf16x8 __attribute__((ext_vector_type(8)));
typedef unsigned short ushort8 __attribute__((ext_vector_type(8)));

static __device__ __forceinline__ unsigned short f2bf(float f) {
  unsigned u = __builtin_bit_cast(unsigned, f);
  return (unsigned short)((u + 0x7fffu + ((u >> 16) & 1u)) >> 16);  // RNE
}
static __device__ __forceinline__ float bf2f(unsigned short h) {
  return __builtin_bit_cast(float, ((unsigned)h) << 16);
}
static __device__ __forceinline__ unsigned pk2(float a, float b) {  // RNE pack
  return (unsigned)f2bf(a) | ((unsigned)f2bf(b) << 16);
}
// static tt in [0,4): select bf16 half of uint2, expand to f32 (1 bit-op)
static __device__ __forceinline__ float upk(uint2 v, int tt) {
  unsigned u = (tt & 2) ? v.y : v.x;
  return (tt & 1) ? __builtin_bit_cast(float, u & 0xffff0000u)
                  : __builtin_bit_cast(float, u << 16);
}
static __device__ __forceinline__ float sigm(float x) {
  return __builtin_amdgcn_rcpf(1.f + __expf(-x));
}
static __device__ __forceinline__ float tanh_fast(float p) {
  float q = __expf(-2.f * fabsf(p));
  float t = (1.f - q) * __builtin_amdgcn_rcpf(1.f + q);
  return __builtin_bit_cast(float, __builtin_bit_cast(unsigned, t) |
                                   (__builtin_bit_cast(unsigned, p) & 0x80000000u));
}

// ---- GRU kernel LDS layout (bytes) ----
#define OFF_WIT 0         // Wi transposed bf16 [768 n][72 k-stride] = 768*144
#define OFF_H0  110592    // h buf0 bf16 [4 real rows + 1 zero row][272] stride 544B
#define OFF_H1  113312    // h buf1
#define OFF_BI  116032    // bi f32 [768]
#define OFF_W64 119104    // Wi row 64 (weight channel) f32 [768]
#define LDS_GRU 122176

#define HSTRIDE 544       // h row stride (row bases hit banks {0,8,16,24})

__global__ __launch_bounds__(512, 2) void gru_kernel(
    const float* __restrict__ particles, const float* __restrict__ weights,
    const float* __restrict__ Wi, const float* __restrict__ bi,
    const float* __restrict__ Wh, const float* __restrict__ bhn,
    unsigned short* __restrict__ hT)
{
  extern __shared__ char smem[];
  const int tid  = threadIdx.x;
  const int lane = tid & 63;
  const int w    = tid >> 6;      // wave id 0..7
  const int l15  = lane & 15;
  const int kg   = lane >> 4;     // k-group 0..3
  const int b0   = blockIdx.x * 4;

  // ---------------- prologue ----------------
  for (int idx = tid; idx < 64 * 768; idx += 512) {
    int k = idx / 768, n = idx - k * 768;
    *(unsigned short*)(smem + OFF_WIT + n * 144 + k * 2) = f2bf(Wi[idx]);
  }
  for (int idx = tid; idx < 768; idx += 512) {
    *(float*)(smem + OFF_BI  + idx * 4) = bi[idx];
    *(float*)(smem + OFF_W64 + idx * 4) = Wi[64 * 768 + idx];
  }
  for (int idx = tid; idx < (2 * 5 * HSTRIDE) / 4; idx += 512)
    ((unsigned*)(smem + OFF_H0))[idx] = 0u;   // h0 = 0 (+ shared zero row 4)

  const int hcol0 = w * 16 + l15;       // p=0 col; p=1 col = hcol0+128
  const float bhn0 = bhn[hcol0];
  const float bhn1 = bhn[hcol0 + 128];

  // Wh -> register B-fragments. Wave w owns N-tiles {w+8j}, j=0..5:
  //   j=0,1 -> r (cols hcol0, hcol0+128); j=2,3 -> z; j=4,5 -> n.
  bf16x8 whb[6][8];
  #pragma unroll
  for (int j = 0; j < 6; ++j) {
    const int tile = w + 8 * j;
    const float* wp = Wh + (size_t)(kg * 8) * 768 + tile * 16 + l15;
    #pragma unroll
    for (int ks = 0; ks < 8; ++ks) {
      ushort8 tmp;
      #pragma unroll
      for (int e = 0; e < 8; ++e)
        tmp[e] = f2bf(wp[(size_t)(ks * 32 + e) * 768]);
      whb[j][ks] = __builtin_bit_cast(bf16x8, tmp);
    }
  }
  __syncthreads();

  // A-fragment source for the recurrence: M-row l15 is real iff l15%4==0
  // (batch = l15>>2, h row l15>>2); fake lanes read the shared zero row 4
  // (same-address broadcast; ~2-way max conflict).
  const unsigned arow = ((l15 & 3) == 0)
                      ? (unsigned)((l15 >> 2) * HSTRIDE + kg * 16)
                      : (unsigned)(4 * HSTRIDE + kg * 16);

  // xp A-row mapping: row l15 <-> (batch=l15>>2, time=l15&3) => C reg r of
  // lane (l15,kg) = xp(batch=kg, time=t0+r).
  const float* pbase = particles +
      ((size_t)(b0 + (l15 >> 2)) * TSEQ + (l15 & 3)) * DPDIM + kg * 8;
  const float* wbase = weights + (size_t)(b0 + kg) * TSEQ;

  f32x4 acc[6];
  uint2 xpk[6];
  float hreg0 = 0.f, hreg1 = 0.f;

  for (int g = 0; g < 64; ++g) {
    const int t0 = g * 4;

    // ---------------- xp phase: project inputs for t0..t0+3 ----------------
    // C-init with bias + weight-channel term (replaces zero-init + fold).
    {
      f32x4 wv = *(const f32x4*)(wbase + t0);
      #pragma unroll
      for (int j = 0; j < 6; ++j) {
        const int col = hcol0 + 128 * j;
        const float biv  = *(const float*)(smem + OFF_BI  + col * 4);
        const float w64v = *(const float*)(smem + OFF_W64 + col * 4);
        acc[j][0] = biv + wv[0] * w64v;
        acc[j][1] = biv + wv[1] * w64v;
        acc[j][2] = biv + wv[2] * w64v;
        acc[j][3] = biv + wv[3] * w64v;
      }
    }
    #pragma unroll
    for (int ks = 0; ks < 2; ++ks) {
      const float* pp = pbase + (size_t)t0 * DPDIM + ks * 32;
      f32x4 pa = *(const f32x4*)pp;
      f32x4 pb = *(const f32x4*)(pp + 4);
      ushort8 tmp;
      tmp[0] = f2bf(pa[0]); tmp[1] = f2bf(pa[1]); tmp[2] = f2bf(pa[2]); tmp[3] = f2bf(pa[3]);
      tmp[4] = f2bf(pb[0]); tmp[5] = f2bf(pb[1]); tmp[6] = f2bf(pb[2]); tmp[7] = f2bf(pb[3]);
      bf16x8 af = __builtin_bit_cast(bf16x8, tmp);
      #pragma unroll
      for (int j = 0; j < 6; ++j) {
        const int n = hcol0 + 128 * j;
        bf16x8 bf = *(const bf16x8*)(smem + OFF_WIT + n * 144 + ks * 64 + kg * 16);
        acc[j] = __builtin_amdgcn_mfma_f32_16x16x32_bf16(af, bf, acc[j], 0, 0, 0);
      }
    }
    // pack xp -> 12 persistent regs (bf16 pairs; times 0..3 per j)
    #pragma unroll
    for (int j = 0; j < 6; ++j) {
      xpk[j].x = pk2(acc[j][0], acc[j][1]);
      xpk[j].y = pk2(acc[j][2], acc[j][3]);
    }

    // ---------------- 4 GRU steps ----------------
    #pragma unroll
    for (int tt = 0; tt < 4; ++tt) {
      const int t     = t0 + tt;
      const int rboff = (t & 1) ? OFF_H1 : OFF_H0;   // read buffer
      const int wboff = (t & 1) ? OFF_H0 : OFF_H1;   // write buffer
      // C-init: r/z gates get xp; n gates get bhn (so acc = bhn + h.Wh_n).
      acc[0][0] = upk(xpk[0], tt);
      acc[1][0] = upk(xpk[1], tt);
      acc[2][0] = upk(xpk[2], tt);
      acc[3][0] = upk(xpk[3], tt);
      acc[4][0] = bhn0;
      acc[5][0] = bhn1;
      const char* hb = smem + rboff;
      #pragma unroll
      for (int ks = 0; ks < 8; ++ks) {
        bf16x8 af = *(const bf16x8*)(hb + arow + ks * 64);
        #pragma unroll
        for (int j = 0; j < 6; ++j)
          acc[j] = __builtin_amdgcn_mfma_f32_16x16x32_bf16(af, whb[j][ks], acc[j], 0, 0, 0);
      }
      // Gates (reg 0 = batch kg): acc[0/1]=xr+hp_r, acc[2/3]=xz+hp_z,
      // acc[4/5]=bhn+hp_n; xn from packed regs; previous h is hreg.
      float rr0 = sigm(acc[0][0]);
      float zz0 = sigm(acc[2][0]);
      float nn0 = tanh_fast(upk(xpk[4], tt) + rr0 * acc[4][0]);
      unsigned short h0u = f2bf(nn0 + zz0 * (hreg0 - nn0));
      hreg0 = bf2f(h0u);
      float rr1 = sigm(acc[1][0]);
      float zz1 = sigm(acc[3][0]);
      float nn1 = tanh_fast(upk(xpk[5], tt) + rr1 * acc[5][0]);
      unsigned short h1u = f2bf(nn1 + zz1 * (hreg1 - nn1));
      hreg1 = bf2f(h1u);
      *(unsigned short*)(smem + wboff + kg * HSTRIDE + hcol0 * 2)         = h0u;
      *(unsigned short*)(smem + wboff + kg * HSTRIDE + (hcol0 + 128) * 2) = h1u;
      __syncthreads();
    }
  }

  // epilogue: final h lives in registers -> store directly
  hT[(size_t)(b0 + kg) * 256 + hcol0]       = f2bf(hreg0);
  hT[(size_t)(b0 + kg) * 256 + hcol0 + 128] = f2bf(hreg1);
}

// ---- Head kernel LDS layout ----
#define HOFF_XA 0         // x tile bf16 [32][296] stride 592B
#define HOFF_B  37888     // B stage bf16 [256 n][40 k] stride 80B
#define HOFF_H1 58368     // h1 bf16 [32][264] stride 528B
#define HOFF_H2 92160
#define HOFF_B1 125952
#define HOFF_B2 126976
#define HOFF_W3 128000
#define LDS_HEAD 129024

#define HROWS 32          // rows per head block (64 blocks = 32 rows x 2 critics)

__global__ __launch_bounds__(256, 2) void head_kernel(
    const unsigned short* __restrict__ hT, const float* __restrict__ action,
    const float* __restrict__ time_idx, const float* __restrict__ W1,
    const float* __restrict__ b1, const float* __restrict__ W2,
    const float* __restrict__ b2, const float* __restrict__ W3,
    const float* __restrict__ b3, float* __restrict__ out)
{
  extern __shared__ char smem[];
  const int tid  = threadIdx.x;
  const int lane = tid & 63;
  const int w    = tid >> 6;
  const int l15  = lane & 15;
  const int kg   = lane >> 4;
  const int c    = blockIdx.x & 1;
  const int rt   = blockIdx.x >> 1;
  const int r0   = rt * HROWS;

  if (tid < 256) {
    *(float*)(smem + HOFF_B1 + tid * 4) = b1[c * 256 + tid];
    *(float*)(smem + HOFF_B2 + tid * 4) = b2[c * 256 + tid];
    *(float*)(smem + HOFF_W3 + tid * 4) = W3[c * 256 + tid];
  }
  // x = [h | action | t/100 | zero-pad to 288]
  for (int idx = tid; idx < HROWS * 296; idx += 256) {
    int row = idx / 296, k = idx - row * 296;
    unsigned short v;
    if (k < 256)       v = hT[(r0 + row) * 256 + k];
    else if (k < 264)  v = f2bf(action[(r0 + row) * 8 + (k - 256)]);
    else if (k == 264) v = f2bf(time_idx[r0 + row] * 0.01f);
    else               v = 0;
    *(unsigned short*)(smem + HOFF_XA + row * 592 + k * 2) = v;
  }

  f32x4 acc[2][4];
  const f32x4 fzero = {0.f, 0.f, 0.f, 0.f};

  // ---- layer 1: h1 = relu(x @ W1[c] + b1[c]), K = 265 padded to 288 ----
  #pragma unroll
  for (int mt = 0; mt < 2; ++mt)
    #pragma unroll
    for (int i = 0; i < 4; ++i) acc[mt][i] = fzero;
  for (int ks = 0; ks < 9; ++ks) {
    for (int idx = tid; idx < 32 * 256; idx += 256) {
      int kk = idx >> 8, n = idx & 255;
      int kglob = ks * 32 + kk;
      float v = (kglob < 265) ? W1[((size_t)c * 265 + kglob) * 256 + n] : 0.f;
      *(unsigned short*)(smem + HOFF_B + n * 80 + kk * 2) = f2bf(v);
    }
    __syncthreads();
    bf16x8 bfr[4];
    #pragma unroll
    for (int i = 0; i < 4; ++i)
      bfr[i] = *(const bf16x8*)(smem + HOFF_B + ((w * 4 + i) * 16 + l15) * 80 + kg * 16);
    #pragma unroll
    for (int mt = 0; mt < 2; ++mt) {
      bf16x8 af = *(const bf16x8*)(smem + HOFF_XA + (mt * 16 + l15) * 592 + ks * 64 + kg * 16);
      #pragma unroll
      for (int i = 0; i < 4; ++i)
        acc[mt][i] = __builtin_amdgcn_mfma_f32_16x16x32_bf16(af, bfr[i], acc[mt][i], 0, 0, 0);
    }
    __syncthreads();
  }
  #pragma unroll
  for (int mt = 0; mt < 2; ++mt)
    #pragma unroll
    for (int i = 0; i < 4; ++i) {
      int col = (w * 4 + i) * 16 + l15;
      float bv = *(const float*)(smem + HOFF_B1 + col * 4);
      #pragma unroll
      for (int r = 0; r < 4; ++r) {
        float v = acc[mt][i][r] + bv; v = v > 0.f ? v : 0.f;
        *(unsigned short*)(smem + HOFF_H1 + (mt * 16 + kg * 4 + r) * 528 + col * 2) = f2bf(v);
      }
    }
  __syncthreads();

  // ---- layer 2: h2 = relu(h1 @ W2[c] + b2[c]), K = 256 ----
  #pragma unroll
  for (int mt = 0; mt < 2; ++mt)
    #pragma unroll
    for (int i = 0; i < 4; ++i) acc[mt][i] = fzero;
  for (int ks = 0; ks < 8; ++ks) {
    for (int idx = tid; idx < 32 * 256; idx += 256) {
      int kk = idx >> 8, n = idx & 255;
      float v = W2[((size_t)c * 256 + ks * 32 + kk) * 256 + n];
      *(unsigned short*)(smem + HOFF_B + n * 80 + kk * 2) = f2bf(v);
    }
    __syncthreads();
    bf16x8 bfr[4];
    #pragma unroll
    for (int i = 0; i < 4; ++i)
      bfr[i] = *(const bf16x8*)(smem + HOFF_B + ((w * 4 + i) * 16 + l15) * 80 + kg * 16);
    #pragma unroll
    for (int mt = 0; mt < 2; ++mt) {
      bf16x8 af = *(const bf16x8*)(smem + HOFF_H1 + (mt * 16 + l15) * 528 + ks * 64 + kg * 16);
      #pragma unroll
      for (int i = 0; i < 4; ++i)
        acc[mt][i] = __builtin_amdgcn_mfma_f32_16x16x32_bf16(af, bfr[i], acc[mt][i], 0, 0, 0);
    }
    __syncthreads();
  }
  #pragma unroll
  for (int mt = 0; mt < 2; ++mt)
    #pragma unroll
    for (int i = 0; i < 4; ++i) {
      int col = (w * 4 + i) * 16 + l15;
      float bv = *(const float*)(smem + HOFF_B2 + col * 4);
      #pragma unroll
      for (int r = 0; r < 4; ++r) {
        float v = acc[mt][i][r] + bv; v = v > 0.f ? v : 0.f;
        *(unsigned short*)(smem + HOFF_H2 + (mt * 16 + kg * 4 + r) * 528 + col * 2) = f2bf(v);
      }
    }
  __syncthreads();

  // ---- layer 3: v = h2 @ W3[c] + b3[c] (VALU dot, 4 threads/row) ----
  {
    int row = tid >> 2, q = tid & 3;
    if (row < HROWS) {
      float s = 0.f;
      #pragma unroll
      for (int i = 0; i < 16; ++i) {
        uint2 hh = *(const uint2*)(smem + HOFF_H2 + row * 528 + (q * 64 + i * 4) * 2);
        const float* w3p = (const float*)(smem + HOFF_W3) + q * 64 + i * 4;
        s += bf2f((unsigned short)hh.x)         * w3p[0];
        s += bf2f((unsigned short)(hh.x >> 16)) * w3p[1];
        s += bf2f((unsigned short)hh.y)         * w3p[2];
        s += bf2f((unsigned short)(hh.y >> 16)) * w3p[3];
      }
      s += __shfl_xor(s, 1);
      s += __shfl_xor(s, 2);
      if (q == 0) out[(r0 + row) * 2 + c] = s + b3[c];
    }
  }
}

extern "C" void kernel_launch(void* const* d_in, const int* in_sizes, int n_in,
                              void* d_out, int out_size, void* d_ws, size_t ws_size,
                              hipStream_t stream) {
  const float* particles = (const float*)d_in[0];
  const float* weights   = (const float*)d_in[1];
  const float* action    = (const float*)d_in[2];
  const float* time_idx  = (const float*)d_in[3];
  const float* Wi        = (const float*)d_in[4];
  const float* bi        = (const float*)d_in[5];
  const float* Wh        = (const float*)d_in[6];
  const float* bhn       = (const float*)d_in[7];
  const float* W1        = (const float*)d_in[8];
  const float* b1        = (const float*)d_in[9];
  const float* W2        = (const float*)d_in[10];
  const float* b2        = (const float*)d_in[11];
  const float* W3        = (const float*)d_in[12];
  const float* b3        = (const float*)d_in[13];
  unsigned short* hT = (unsigned short*)d_ws;   // [1024][256] bf16
  float* out = (float*)d_out;

  (void)hipFuncSetAttribute((const void*)gru_kernel,
                            hipFuncAttributeMaxDynamicSharedMemorySize, LDS_GRU);
  (void)hipFuncSetAttribute((const void*)head_kernel,
                            hipFuncAttributeMaxDynamicSharedMemorySize, LDS_HEAD);

  hipLaunchKernelGGL(gru_kernel, dim3(256), dim3(512), LDS_GRU, stream,
                     particles, weights, Wi, bi, Wh, bhn, hT);
  hipLaunchKernelGGL(head_kernel, dim3(64), dim3(256), LDS_HEAD, stream,
                     hT, action, time_idx, W1, b1, W2, b2, W3, b3, out);
}

// Round 7
// 794.497 us; speedup vs baseline: 2.1443x; 2.0594x over previous
//
#include <hip/hip_runtime.h>

// ---------------------------------------------------------------------------
// CriticNetwork: GRU over T=256 steps (B=1024, H=256, F=65) + 2-critic MLP.
// Kernel 1 (gru_kernel): persistent, 256 blocks x 512 thr (8 waves, 2/SIMD).
//   REGISTER WALL (r5/r6 lessons): whb = 384 KB/CU regardless of wave split;
//   2 waves/SIMD is the occupancy ceiling. Spare regs ~12: xp CANNOT live in
//   registers alongside the 8-deep compiler-scheduled ds_read loop (r6 spill,
//   2.8 GB fetch). Manual pipelines/masked loads/setprio also proven bad (r4).
//   Structure = r3 skeleton exactly, plus:
//   - xp LDS layout [j][tt][col][kg] (addr j*4096+tt*1024+col*8+kg*2):
//     conflict-free for BOTH the 24 ds_write_b16/group and the 6 u16
//     reads/step (64 lanes -> 32 banks, kg-pairs share dwords). r3's old
//     col*32+kg*8 layout was 4-way conflicted on every access.
//   - C-init folding (r4-proven, 0 extra persistent regs): xp-phase C-in =
//     bi + wv*w64; recurrence C-in = xp (r/z gates) / bhn (n gate). Unread
//     C rows carry stale finite values (rowwise-independent MFMA, never read).
//   - h in a register per lane; LDS h write only for other waves' A-reads;
//     fake A-lanes broadcast-read shared zero row 4 (5-row buf, stride 544).
// Kernel 2 (head_kernel): twin critic MLPs, 64 blocks x 32 rows (r4-proven).
// ---------------------------------------------------------------------------

#define TSEQ 256
#define DPDIM 64

typedef float f32x4 __attribute__((ext_vector_type(4)));
typedef __bf16 bf16x8 __attribute__((ext_vector_type(8)));
typedef unsigned short ushort8 __attribute__((ext_vector_type(8)));

static __device__ __forceinline__ unsigned short f2bf(float f) {
  unsigned u = __builtin_bit_cast(unsigned, f);
  return (unsigned short)((u + 0x7fffu + ((u >> 16) & 1u)) >> 16);  // RNE
}
static __device__ __forceinline__ float bf2f(unsigned short h) {
  return __builtin_bit_cast(float, ((unsigned)h) << 16);
}
static __device__ __forceinline__ float sigm(float x) {
  return __builtin_amdgcn_rcpf(1.f + __expf(-x));
}
static __device__ __forceinline__ float tanh_fast(float p) {
  float q = __expf(-2.f * fabsf(p));
  float t = (1.f - q) * __builtin_amdgcn_rcpf(1.f + q);
  return __builtin_bit_cast(float, __builtin_bit_cast(unsigned, t) |
                                   (__builtin_bit_cast(unsigned, p) & 0x80000000u));
}

// ---- GRU kernel LDS layout (bytes) ----
#define OFF_WIT 0         // Wi transposed bf16 [768 n][72 k-stride] = 768*144
#define OFF_XP  110592    // xp bf16 [6 j][4 tt][128 col][4 kg] = 24576
#define OFF_H0  135168    // h buf0 bf16 [4 real rows + 1 zero row][272] stride 544B
#define OFF_H1  137888    // h buf1
#define OFF_BI  140608    // bi f32 [768]
#define OFF_W64 143680    // Wi row 64 (weight channel) f32 [768]
#define LDS_GRU 146752

#define HSTRIDE 544       // h row stride (row bases hit banks {0,8,16,24})

__global__ __launch_bounds__(512, 2) void gru_kernel(
    const float* __restrict__ particles, const float* __restrict__ weights,
    const float* __restrict__ Wi, const float* __restrict__ bi,
    const float* __restrict__ Wh, const float* __restrict__ bhn,
    unsigned short* __restrict__ hT)
{
  extern __shared__ char smem[];
  const int tid  = threadIdx.x;
  const int lane = tid & 63;
  const int w    = tid >> 6;      // wave id 0..7
  const int l15  = lane & 15;
  const int kg   = lane >> 4;     // k-group 0..3
  const int b0   = blockIdx.x * 4;

  // ---------------- prologue ----------------
  for (int idx = tid; idx < 64 * 768; idx += 512) {
    int k = idx / 768, n = idx - k * 768;
    *(unsigned short*)(smem + OFF_WIT + n * 144 + k * 2) = f2bf(Wi[idx]);
  }
  for (int idx = tid; idx < 768; idx += 512) {
    *(float*)(smem + OFF_BI  + idx * 4) = bi[idx];
    *(float*)(smem + OFF_W64 + idx * 4) = Wi[64 * 768 + idx];
  }
  for (int idx = tid; idx < (2 * 5 * HSTRIDE) / 4; idx += 512)
    ((unsigned*)(smem + OFF_H0))[idx] = 0u;   // h0 = 0 (+ shared zero row 4)

  const int hcol0 = w * 16 + l15;       // p=0 col; p=1 col = hcol0+128
  const float bhn0 = bhn[hcol0];
  const float bhn1 = bhn[hcol0 + 128];

  // Wh -> register B-fragments. Wave w owns N-tiles {w+8j}, j=0..5:
  //   j=0,1 -> r (cols hcol0, hcol0+128); j=2,3 -> z; j=4,5 -> n.
  bf16x8 whb[6][8];
  #pragma unroll
  for (int j = 0; j < 6; ++j) {
    const int tile = w + 8 * j;
    const float* wp = Wh + (size_t)(kg * 8) * 768 + tile * 16 + l15;
    #pragma unroll
    for (int ks = 0; ks < 8; ++ks) {
      ushort8 tmp;
      #pragma unroll
      for (int e = 0; e < 8; ++e)
        tmp[e] = f2bf(wp[(size_t)(ks * 32 + e) * 768]);
      whb[j][ks] = __builtin_bit_cast(bf16x8, tmp);
    }
  }
  __syncthreads();

  // A-fragment source for the recurrence: M-row l15 is real iff l15%4==0
  // (batch = l15>>2, h row l15>>2); fake lanes read the shared zero row 4
  // (same-address broadcast; ~2-way max conflict).
  const unsigned arow = ((l15 & 3) == 0)
                      ? (unsigned)((l15 >> 2) * HSTRIDE + kg * 16)
                      : (unsigned)(4 * HSTRIDE + kg * 16);

  // xp A-row mapping: row l15 <-> (batch=l15>>2, time=l15&3) => C reg r of
  // lane (l15,kg) = xp(batch=kg, time=t0+r), i.e. writer lane == reader lane.
  const float* pbase = particles +
      ((size_t)(b0 + (l15 >> 2)) * TSEQ + (l15 & 3)) * DPDIM + kg * 8;
  const float* wbase = weights + (size_t)(b0 + kg) * TSEQ;

  // lane's conflict-free XP slot: + j*4096 + tt*1024
  char* const xpb = smem + OFF_XP + hcol0 * 8 + kg * 2;

  f32x4 acc[6];
  const f32x4 fzero = {0.f, 0.f, 0.f, 0.f};
  #pragma unroll
  for (int j = 0; j < 6; ++j) acc[j] = fzero;   // one-time init (stale later, ok)
  float hreg0 = 0.f, hreg1 = 0.f;

  for (int g = 0; g < 64; ++g) {
    const int t0 = g * 4;

    // ---------------- xp phase: project inputs for t0..t0+3 ----------------
    // C-init with bias + weight-channel term (replaces zero-init + fold pass).
    {
      f32x4 wv = *(const f32x4*)(wbase + t0);
      #pragma unroll
      for (int j = 0; j < 6; ++j) {
        const int col = hcol0 + 128 * j;
        const float biv  = *(const float*)(smem + OFF_BI  + col * 4);
        const float w64v = *(const float*)(smem + OFF_W64 + col * 4);
        acc[j][0] = biv + wv[0] * w64v;
        acc[j][1] = biv + wv[1] * w64v;
        acc[j][2] = biv + wv[2] * w64v;
        acc[j][3] = biv + wv[3] * w64v;
      }
    }
    #pragma unroll
    for (int ks = 0; ks < 2; ++ks) {
      const float* pp = pbase + (size_t)t0 * DPDIM + ks * 32;
      f32x4 pa = *(const f32x4*)pp;
      f32x4 pb = *(const f32x4*)(pp + 4);
      ushort8 tmp;
      tmp[0] = f2bf(pa[0]); tmp[1] = f2bf(pa[1]); tmp[2] = f2bf(pa[2]); tmp[3] = f2bf(pa[3]);
      tmp[4] = f2bf(pb[0]); tmp[5] = f2bf(pb[1]); tmp[6] = f2bf(pb[2]); tmp[7] = f2bf(pb[3]);
      bf16x8 af = __builtin_bit_cast(bf16x8, tmp);
      #pragma unroll
      for (int j = 0; j < 6; ++j) {
        const int n = hcol0 + 128 * j;
        bf16x8 bf = *(const bf16x8*)(smem + OFF_WIT + n * 144 + ks * 64 + kg * 16);
        acc[j] = __builtin_amdgcn_mfma_f32_16x16x32_bf16(af, bf, acc[j], 0, 0, 0);
      }
    }
    // park xp in the conflict-free LDS slot (writer == only reader lane)
    #pragma unroll
    for (int j = 0; j < 6; ++j) {
      #pragma unroll
      for (int r = 0; r < 4; ++r)
        *(unsigned short*)(xpb + j * 4096 + r * 1024) = f2bf(acc[j][r]);
    }

    // ---------------- 4 GRU steps ----------------
    #pragma unroll
    for (int tt = 0; tt < 4; ++tt) {
      const int t     = t0 + tt;
      const int rboff = (t & 1) ? OFF_H1 : OFF_H0;   // read buffer
      const int wboff = (t & 1) ? OFF_H0 : OFF_H1;   // write buffer
      // C-init: r/z gates get xp (conflict-free u16 reads); n gates get bhn.
      acc[0][0] = bf2f(*(const unsigned short*)(xpb + 0 * 4096 + tt * 1024));
      acc[1][0] = bf2f(*(const unsigned short*)(xpb + 1 * 4096 + tt * 1024));
      acc[2][0] = bf2f(*(const unsigned short*)(xpb + 2 * 4096 + tt * 1024));
      acc[3][0] = bf2f(*(const unsigned short*)(xpb + 3 * 4096 + tt * 1024));
      acc[4][0] = bhn0;
      acc[5][0] = bhn1;
      const char* hb = smem + rboff;
      #pragma unroll
      for (int ks = 0; ks < 8; ++ks) {
        bf16x8 af = *(const bf16x8*)(hb + arow + ks * 64);
        #pragma unroll
        for (int j = 0; j < 6; ++j)
          acc[j] = __builtin_amdgcn_mfma_f32_16x16x32_bf16(af, whb[j][ks], acc[j], 0, 0, 0);
      }
      // Gates (reg 0 = batch kg): acc[0/1]=xr+hp_r, acc[2/3]=xz+hp_z,
      // acc[4/5]=bhn+hp_n; xn from the slot; previous h is hreg.
      float xn0 = bf2f(*(const unsigned short*)(xpb + 4 * 4096 + tt * 1024));
      float xn1 = bf2f(*(const unsigned short*)(xpb + 5 * 4096 + tt * 1024));
      float rr0 = sigm(acc[0][0]);
      float zz0 = sigm(acc[2][0]);
      float nn0 = tanh_fast(xn0 + rr0 * acc[4][0]);
      unsigned short h0u = f2bf(nn0 + zz0 * (hreg0 - nn0));
      hreg0 = bf2f(h0u);
      float rr1 = sigm(acc[1][0]);
      float zz1 = sigm(acc[3][0]);
      float nn1 = tanh_fast(xn1 + rr1 * acc[5][0]);
      unsigned short h1u = f2bf(nn1 + zz1 * (hreg1 - nn1));
      hreg1 = bf2f(h1u);
      *(unsigned short*)(smem + wboff + kg * HSTRIDE + hcol0 * 2)         = h0u;
      *(unsigned short*)(smem + wboff + kg * HSTRIDE + (hcol0 + 128) * 2) = h1u;
      __syncthreads();
    }
  }

  // epilogue: final h lives in registers -> store directly
  hT[(size_t)(b0 + kg) * 256 + hcol0]       = f2bf(hreg0);
  hT[(size_t)(b0 + kg) * 256 + hcol0 + 128] = f2bf(hreg1);
}

// ---- Head kernel LDS layout ----
#define HOFF_XA 0         // x tile bf16 [32][296] stride 592B
#define HOFF_B  37888     // B stage bf16 [256 n][40 k] stride 80B
#define HOFF_H1 58368     // h1 bf16 [32][264] stride 528B
#define HOFF_H2 92160
#define HOFF_B1 125952
#define HOFF_B2 126976
#define HOFF_W3 128000
#define LDS_HEAD 129024

#define HROWS 32          // rows per head block (64 blocks = 32 rows x 2 critics)

__global__ __launch_bounds__(256, 2) void head_kernel(
    const unsigned short* __restrict__ hT, const float* __restrict__ action,
    const float* __restrict__ time_idx, const float* __restrict__ W1,
    const float* __restrict__ b1, const float* __restrict__ W2,
    const float* __restrict__ b2, const float* __restrict__ W3,
    const float* __restrict__ b3, float* __restrict__ out)
{
  extern __shared__ char smem[];
  const int tid  = threadIdx.x;
  const int lane = tid & 63;
  const int w    = tid >> 6;
  const int l15  = lane & 15;
  const int kg   = lane >> 4;
  const int c    = blockIdx.x & 1;
  const int rt   = blockIdx.x >> 1;
  const int r0   = rt * HROWS;

  if (tid < 256) {
    *(float*)(smem + HOFF_B1 + tid * 4) = b1[c * 256 + tid];
    *(float*)(smem + HOFF_B2 + tid * 4) = b2[c * 256 + tid];
    *(float*)(smem + HOFF_W3 + tid * 4) = W3[c * 256 + tid];
  }
  // x = [h | action | t/100 | zero-pad to 288]
  for (int idx = tid; idx < HROWS * 296; idx += 256) {
    int row = idx / 296, k = idx - row * 296;
    unsigned short v;
    if (k < 256)       v = hT[(r0 + row) * 256 + k];
    else if (k < 264)  v = f2bf(action[(r0 + row) * 8 + (k - 256)]);
    else if (k == 264) v = f2bf(time_idx[r0 + row] * 0.01f);
    else               v = 0;
    *(unsigned short*)(smem + HOFF_XA + row * 592 + k * 2) = v;
  }

  f32x4 acc[2][4];
  const f32x4 fzero = {0.f, 0.f, 0.f, 0.f};

  // ---- layer 1: h1 = relu(x @ W1[c] + b1[c]), K = 265 padded to 288 ----
  #pragma unroll
  for (int mt = 0; mt < 2; ++mt)
    #pragma unroll
    for (int i = 0; i < 4; ++i) acc[mt][i] = fzero;
  for (int ks = 0; ks < 9; ++ks) {
    for (int idx = tid; idx < 32 * 256; idx += 256) {
      int kk = idx >> 8, n = idx & 255;
      int kglob = ks * 32 + kk;
      float v = (kglob < 265) ? W1[((size_t)c * 265 + kglob) * 256 + n] : 0.f;
      *(unsigned short*)(smem + HOFF_B + n * 80 + kk * 2) = f2bf(v);
    }
    __syncthreads();
    bf16x8 bfr[4];
    #pragma unroll
    for (int i = 0; i < 4; ++i)
      bfr[i] = *(const bf16x8*)(smem + HOFF_B + ((w * 4 + i) * 16 + l15) * 80 + kg * 16);
    #pragma unroll
    for (int mt = 0; mt < 2; ++mt) {
      bf16x8 af = *(const bf16x8*)(smem + HOFF_XA + (mt * 16 + l15) * 592 + ks * 64 + kg * 16);
      #pragma unroll
      for (int i = 0; i < 4; ++i)
        acc[mt][i] = __builtin_amdgcn_mfma_f32_16x16x32_bf16(af, bfr[i], acc[mt][i], 0, 0, 0);
    }
    __syncthreads();
  }
  #pragma unroll
  for (int mt = 0; mt < 2; ++mt)
    #pragma unroll
    for (int i = 0; i < 4; ++i) {
      int col = (w * 4 + i) * 16 + l15;
      float bv = *(const float*)(smem + HOFF_B1 + col * 4);
      #pragma unroll
      for (int r = 0; r < 4; ++r) {
        float v = acc[mt][i][r] + bv; v = v > 0.f ? v : 0.f;
        *(unsigned short*)(smem + HOFF_H1 + (mt * 16 + kg * 4 + r) * 528 + col * 2) = f2bf(v);
      }
    }
  __syncthreads();

  // ---- layer 2: h2 = relu(h1 @ W2[c] + b2[c]), K = 256 ----
  #pragma unroll
  for (int mt = 0; mt < 2; ++mt)
    #pragma unroll
    for (int i = 0; i < 4; ++i) acc[mt][i] = fzero;
  for (int ks = 0; ks < 8; ++ks) {
    for (int idx = tid; idx < 32 * 256; idx += 256) {
      int kk = idx >> 8, n = idx & 255;
      float v = W2[((size_t)c * 256 + ks * 32 + kk) * 256 + n];
      *(unsigned short*)(smem + HOFF_B + n * 80 + kk * 2) = f2bf(v);
    }
    __syncthreads();
    bf16x8 bfr[4];
    #pragma unroll
    for (int i = 0; i < 4; ++i)
      bfr[i] = *(const bf16x8*)(smem + HOFF_B + ((w * 4 + i) * 16 + l15) * 80 + kg * 16);
    #pragma unroll
    for (int mt = 0; mt < 2; ++mt) {
      bf16x8 af = *(const bf16x8*)(smem + HOFF_H1 + (mt * 16 + l15) * 528 + ks * 64 + kg * 16);
      #pragma unroll
      for (int i = 0; i < 4; ++i)
        acc[mt][i] = __builtin_amdgcn_mfma_f32_16x16x32_bf16(af, bfr[i], acc[mt][i], 0, 0, 0);
    }
    __syncthreads();
  }
  #pragma unroll
  for (int mt = 0; mt < 2; ++mt)
    #pragma unroll
    for (int i = 0; i < 4; ++i) {
      int col = (w * 4 + i) * 16 + l15;
      float bv = *(const float*)(smem + HOFF_B2 + col * 4);
      #pragma unroll
      for (int r = 0; r < 4; ++r) {
        float v = acc[mt][i][r] + bv; v = v > 0.f ? v : 0.f;
        *(unsigned short*)(smem + HOFF_H2 + (mt * 16 + kg * 4 + r) * 528 + col * 2) = f2bf(v);
      }
    }
  __syncthreads();

  // ---- layer 3: v = h2 @ W3[c] + b3[c] (VALU dot, 4 threads/row) ----
  {
    int row = tid >> 2, q = tid & 3;
    if (row < HROWS) {
      float s = 0.f;
      #pragma unroll
      for (int i = 0; i < 16; ++i) {
        uint2 hh = *(const uint2*)(smem + HOFF_H2 + row * 528 + (q * 64 + i * 4) * 2);
        const float* w3p = (const float*)(smem + HOFF_W3) + q * 64 + i * 4;
        s += bf2f((unsigned short)hh.x)         * w3p[0];
        s += bf2f((unsigned short)(hh.x >> 16)) * w3p[1];
        s += bf2f((unsigned short)hh.y)         * w3p[2];
        s += bf2f((unsigned short)(hh.y >> 16)) * w3p[3];
      }
      s += __shfl_xor(s, 1);
      s += __shfl_xor(s, 2);
      if (q == 0) out[(r0 + row) * 2 + c] = s + b3[c];
    }
  }
}

extern "C" void kernel_launch(void* const* d_in, const int* in_sizes, int n_in,
                              void* d_out, int out_size, void* d_ws, size_t ws_size,
                              hipStream_t stream) {
  const float* particles = (const float*)d_in[0];
  const float* weights   = (const float*)d_in[1];
  const float* action    = (const float*)d_in[2];
  const float* time_idx  = (const float*)d_in[3];
  const float* Wi        = (const float*)d_in[4];
  const float* bi        = (const float*)d_in[5];
  const float* Wh        = (const float*)d_in[6];
  const float* bhn       = (const float*)d_in[7];
  const float* W1        = (const float*)d_in[8];
  const float* b1        = (const float*)d_in[9];
  const float* W2        = (const float*)d_in[10];
  const float* b2        = (const float*)d_in[11];
  const float* W3        = (const float*)d_in[12];
  const float* b3        = (const float*)d_in[13];
  unsigned short* hT = (unsigned short*)d_ws;   // [1024][256] bf16
  float* out = (float*)d_out;

  (void)hipFuncSetAttribute((const void*)gru_kernel,
                            hipFuncAttributeMaxDynamicSharedMemorySize, LDS_GRU);
  (void)hipFuncSetAttribute((const void*)head_kernel,
                            hipFuncAttributeMaxDynamicSharedMemorySize, LDS_HEAD);

  hipLaunchKernelGGL(gru_kernel, dim3(256), dim3(512), LDS_GRU, stream,
                     particles, weights, Wi, bi, Wh, bhn, hT);
  hipLaunchKernelGGL(head_kernel, dim3(64), dim3(256), LDS_HEAD, stream,
                     hT, action, time_idx, W1, b1, W2, b2, W3, b3, out);
}

// Round 8
// 725.562 us; speedup vs baseline: 2.3480x; 1.0950x over previous
//
#include <hip/hip_runtime.h>

// ---------------------------------------------------------------------------
// CriticNetwork: GRU over T=256 steps (B=1024, H=256, F=65) + 2-critic MLP.
// Kernel 1 (gru_kernel): persistent, 256 blocks x 512 thr (8 waves, 2/SIMD).
//   REGISTER BUDGET (r5/r6/r7 lessons): whb = 384 KB/CU fixed -> 64 spare
//   regs/lane at 8 waves; {acc 24 + 8-deep af 32 + misc 15} is ~10 over, so
//   the allocator ALWAYS leaks a little; every change must be reg-neutral.
//   r7's C-init folding (+wv/bias live ranges) doubled spill and lost 70us.
//   Structure = r3 skeleton EXACTLY (fzero init, fold-after-MFMA, plain
//   8-deep compiler-scheduled ks loop, 1 barrier/step, hreg in register),
//   with only register-neutral deltas:
//   - xp LDS layout [j][tt][col][kg] (j*4096+tt*1024+col*8+kg*2):
//     conflict-free reads AND writes (64 lanes -> 32 banks, kg-pairs merge
//     in one dword). r3's col*32+kg*8 was 4-way conflicted on every access.
//     (r7-verified: conflicts 3.5e7 -> 7.5e6.)
//   - bhn back in LDS (broadcast read, conflict-free) -> frees 2 VGPRs.
// Kernel 2 (head_kernel): twin critic MLPs, 64 blocks x 32 rows (r4-proven).
// ---------------------------------------------------------------------------

#define TSEQ 256
#define DPDIM 64

typedef float f32x4 __attribute__((ext_vector_type(4)));
typedef __bf16 bf16x8 __attribute__((ext_vector_type(8)));
typedef unsigned short ushort8 __attribute__((ext_vector_type(8)));

static __device__ __forceinline__ unsigned short f2bf(float f) {
  unsigned u = __builtin_bit_cast(unsigned, f);
  return (unsigned short)((u + 0x7fffu + ((u >> 16) & 1u)) >> 16);  // RNE
}
static __device__ __forceinline__ float bf2f(unsigned short h) {
  return __builtin_bit_cast(float, ((unsigned)h) << 16);
}
static __device__ __forceinline__ float sigm(float x) {
  return __builtin_amdgcn_rcpf(1.f + __expf(-x));
}
static __device__ __forceinline__ float tanh_fast(float p) {
  float q = __expf(-2.f * fabsf(p));
  float t = (1.f - q) * __builtin_amdgcn_rcpf(1.f + q);
  return __builtin_bit_cast(float, __builtin_bit_cast(unsigned, t) |
                                   (__builtin_bit_cast(unsigned, p) & 0x80000000u));
}

// ---- GRU kernel LDS layout (bytes) ----
#define OFF_WIT 0         // Wi transposed bf16 [768 n][72 k-stride] = 768*144
#define OFF_XP  110592    // xp bf16 [6 j][4 tt][128 col][4 kg] = 24576
#define OFF_H0  135168    // h buf0 bf16 [4 real rows + 1 zero row][272] stride 544B
#define OFF_H1  137888    // h buf1
#define OFF_BI  140608    // bi f32 [768]
#define OFF_W64 143680    // Wi row 64 (weight channel) f32 [768]
#define OFF_BHN 146752    // bhn f32 [256]
#define LDS_GRU 147776

#define HSTRIDE 544       // h row stride (row bases hit banks {0,8,16,24})

__global__ __launch_bounds__(512, 2) void gru_kernel(
    const float* __restrict__ particles, const float* __restrict__ weights,
    const float* __restrict__ Wi, const float* __restrict__ bi,
    const float* __restrict__ Wh, const float* __restrict__ bhn,
    unsigned short* __restrict__ hT)
{
  extern __shared__ char smem[];
  const int tid  = threadIdx.x;
  const int lane = tid & 63;
  const int w    = tid >> 6;      // wave id 0..7
  const int l15  = lane & 15;
  const int kg   = lane >> 4;     // k-group 0..3
  const int b0   = blockIdx.x * 4;

  // ---------------- prologue ----------------
  for (int idx = tid; idx < 64 * 768; idx += 512) {
    int k = idx / 768, n = idx - k * 768;
    *(unsigned short*)(smem + OFF_WIT + n * 144 + k * 2) = f2bf(Wi[idx]);
  }
  for (int idx = tid; idx < 768; idx += 512) {
    *(float*)(smem + OFF_BI  + idx * 4) = bi[idx];
    *(float*)(smem + OFF_W64 + idx * 4) = Wi[64 * 768 + idx];
  }
  if (tid < 256) *(float*)(smem + OFF_BHN + tid * 4) = bhn[tid];
  for (int idx = tid; idx < (2 * 5 * HSTRIDE) / 4; idx += 512)
    ((unsigned*)(smem + OFF_H0))[idx] = 0u;   // h0 = 0 (+ shared zero row 4)

  const int hcol0 = w * 16 + l15;       // p=0 col; p=1 col = hcol0+128

  // Wh -> register B-fragments. Wave w owns N-tiles {w+8j}, j=0..5:
  //   j=0,1 -> r (cols hcol0, hcol0+128); j=2,3 -> z; j=4,5 -> n.
  bf16x8 whb[6][8];
  #pragma unroll
  for (int j = 0; j < 6; ++j) {
    const int tile = w + 8 * j;
    const float* wp = Wh + (size_t)(kg * 8) * 768 + tile * 16 + l15;
    #pragma unroll
    for (int ks = 0; ks < 8; ++ks) {
      ushort8 tmp;
      #pragma unroll
      for (int e = 0; e < 8; ++e)
        tmp[e] = f2bf(wp[(size_t)(ks * 32 + e) * 768]);
      whb[j][ks] = __builtin_bit_cast(bf16x8, tmp);
    }
  }
  __syncthreads();

  // A-fragment source for the recurrence: M-row l15 is real iff l15%4==0
  // (batch = l15>>2, h row l15>>2); fake lanes read the shared zero row 4
  // (same-address broadcast; ~2-way max conflict).
  const unsigned arow = ((l15 & 3) == 0)
                      ? (unsigned)((l15 >> 2) * HSTRIDE + kg * 16)
                      : (unsigned)(4 * HSTRIDE + kg * 16);

  // xp A-row mapping: row l15 <-> (batch=l15>>2, time=l15&3) => C reg r of
  // lane (l15,kg) = xp(batch=kg, time=t0+r), i.e. writer lane == reader lane.
  const float* pbase = particles +
      ((size_t)(b0 + (l15 >> 2)) * TSEQ + (l15 & 3)) * DPDIM + kg * 8;
  const float* wbase = weights + (size_t)(b0 + kg) * TSEQ;

  // lane's conflict-free XP slot: + j*4096 + tt*1024
  char* const xpb = smem + OFF_XP + hcol0 * 8 + kg * 2;

  f32x4 acc[6];
  const f32x4 fzero = {0.f, 0.f, 0.f, 0.f};
  float hreg0 = 0.f, hreg1 = 0.f;

  for (int g = 0; g < 64; ++g) {
    const int t0 = g * 4;

    // ---------------- xp phase: project inputs for t0..t0+3 ----------------
    #pragma unroll
    for (int j = 0; j < 6; ++j) acc[j] = fzero;
    #pragma unroll
    for (int ks = 0; ks < 2; ++ks) {
      const float* pp = pbase + (size_t)t0 * DPDIM + ks * 32;
      f32x4 pa = *(const f32x4*)pp;
      f32x4 pb = *(const f32x4*)(pp + 4);
      ushort8 tmp;
      tmp[0] = f2bf(pa[0]); tmp[1] = f2bf(pa[1]); tmp[2] = f2bf(pa[2]); tmp[3] = f2bf(pa[3]);
      tmp[4] = f2bf(pb[0]); tmp[5] = f2bf(pb[1]); tmp[6] = f2bf(pb[2]); tmp[7] = f2bf(pb[3]);
      bf16x8 af = __builtin_bit_cast(bf16x8, tmp);
      #pragma unroll
      for (int j = 0; j < 6; ++j) {
        const int n = hcol0 + 128 * j;
        bf16x8 bf = *(const bf16x8*)(smem + OFF_WIT + n * 144 + ks * 64 + kg * 16);
        acc[j] = __builtin_amdgcn_mfma_f32_16x16x32_bf16(af, bf, acc[j], 0, 0, 0);
      }
    }
    // fold bias + weight-channel, park xp in conflict-free LDS slot
    // (writer lane == only reader lane; banks distinct across the wave).
    {
      f32x4 wv = *(const f32x4*)(wbase + t0);
      #pragma unroll
      for (int j = 0; j < 6; ++j) {
        const int col = hcol0 + 128 * j;
        const float biv  = *(const float*)(smem + OFF_BI  + col * 4);
        const float w64v = *(const float*)(smem + OFF_W64 + col * 4);
        #pragma unroll
        for (int r = 0; r < 4; ++r)
          *(unsigned short*)(xpb + j * 4096 + r * 1024) =
              f2bf(acc[j][r] + biv + wv[r] * w64v);
      }
    }

    // ---------------- 4 GRU steps ----------------
    #pragma unroll
    for (int tt = 0; tt < 4; ++tt) {
      const int t     = t0 + tt;
      const int rboff = (t & 1) ? OFF_H1 : OFF_H0;   // read buffer
      const int wboff = (t & 1) ? OFF_H0 : OFF_H1;   // write buffer
      #pragma unroll
      for (int j = 0; j < 6; ++j) acc[j] = fzero;
      const char* hb = smem + rboff;
      #pragma unroll
      for (int ks = 0; ks < 8; ++ks) {
        bf16x8 af = *(const bf16x8*)(hb + arow + ks * 64);
        #pragma unroll
        for (int j = 0; j < 6; ++j)
          acc[j] = __builtin_amdgcn_mfma_f32_16x16x32_bf16(af, whb[j][ks], acc[j], 0, 0, 0);
      }
      // Gates (reg 0 = batch kg): xp/bhn from conflict-free LDS; h from hreg.
      float xr0 = bf2f(*(const unsigned short*)(xpb + 0 * 4096 + tt * 1024));
      float xr1 = bf2f(*(const unsigned short*)(xpb + 1 * 4096 + tt * 1024));
      float xz0 = bf2f(*(const unsigned short*)(xpb + 2 * 4096 + tt * 1024));
      float xz1 = bf2f(*(const unsigned short*)(xpb + 3 * 4096 + tt * 1024));
      float xn0 = bf2f(*(const unsigned short*)(xpb + 4 * 4096 + tt * 1024));
      float xn1 = bf2f(*(const unsigned short*)(xpb + 5 * 4096 + tt * 1024));
      const float bhv0 = *(const float*)(smem + OFF_BHN + hcol0 * 4);
      const float bhv1 = *(const float*)(smem + OFF_BHN + (hcol0 + 128) * 4);
      float rr0 = sigm(xr0 + acc[0][0]);
      float zz0 = sigm(xz0 + acc[2][0]);
      float nn0 = tanh_fast(xn0 + rr0 * (acc[4][0] + bhv0));
      unsigned short h0u = f2bf(nn0 + zz0 * (hreg0 - nn0));
      hreg0 = bf2f(h0u);
      float rr1 = sigm(xr1 + acc[1][0]);
      float zz1 = sigm(xz1 + acc[3][0]);
      float nn1 = tanh_fast(xn1 + rr1 * (acc[5][0] + bhv1));
      unsigned short h1u = f2bf(nn1 + zz1 * (hreg1 - nn1));
      hreg1 = bf2f(h1u);
      *(unsigned short*)(smem + wboff + kg * HSTRIDE + hcol0 * 2)         = h0u;
      *(unsigned short*)(smem + wboff + kg * HSTRIDE + (hcol0 + 128) * 2) = h1u;
      __syncthreads();
    }
  }

  // epilogue: final h lives in registers -> store directly
  hT[(size_t)(b0 + kg) * 256 + hcol0]       = f2bf(hreg0);
  hT[(size_t)(b0 + kg) * 256 + hcol0 + 128] = f2bf(hreg1);
}

// ---- Head kernel LDS layout ----
#define HOFF_XA 0         // x tile bf16 [32][296] stride 592B
#define HOFF_B  37888     // B stage bf16 [256 n][40 k] stride 80B
#define HOFF_H1 58368     // h1 bf16 [32][264] stride 528B
#define HOFF_H2 92160
#define HOFF_B1 125952
#define HOFF_B2 126976
#define HOFF_W3 128000
#define LDS_HEAD 129024

#define HROWS 32          // rows per head block (64 blocks = 32 rows x 2 critics)

__global__ __launch_bounds__(256, 2) void head_kernel(
    const unsigned short* __restrict__ hT, const float* __restrict__ action,
    const float* __restrict__ time_idx, const float* __restrict__ W1,
    const float* __restrict__ b1, const float* __restrict__ W2,
    const float* __restrict__ b2, const float* __restrict__ W3,
    const float* __restrict__ b3, float* __restrict__ out)
{
  extern __shared__ char smem[];
  const int tid  = threadIdx.x;
  const int lane = tid & 63;
  const int w    = tid >> 6;
  const int l15  = lane & 15;
  const int kg   = lane >> 4;
  const int c    = blockIdx.x & 1;
  const int rt   = blockIdx.x >> 1;
  const int r0   = rt * HROWS;

  if (tid < 256) {
    *(float*)(smem + HOFF_B1 + tid * 4) = b1[c * 256 + tid];
    *(float*)(smem + HOFF_B2 + tid * 4) = b2[c * 256 + tid];
    *(float*)(smem + HOFF_W3 + tid * 4) = W3[c * 256 + tid];
  }
  // x = [h | action | t/100 | zero-pad to 288]
  for (int idx = tid; idx < HROWS * 296; idx += 256) {
    int row = idx / 296, k = idx - row * 296;
    unsigned short v;
    if (k < 256)       v = hT[(r0 + row) * 256 + k];
    else if (k < 264)  v = f2bf(action[(r0 + row) * 8 + (k - 256)]);
    else if (k == 264) v = f2bf(time_idx[r0 + row] * 0.01f);
    else               v = 0;
    *(unsigned short*)(smem + HOFF_XA + row * 592 + k * 2) = v;
  }

  f32x4 acc[2][4];
  const f32x4 fzero = {0.f, 0.f, 0.f, 0.f};

  // ---- layer 1: h1 = relu(x @ W1[c] + b1[c]), K = 265 padded to 288 ----
  #pragma unroll
  for (int mt = 0; mt < 2; ++mt)
    #pragma unroll
    for (int i = 0; i < 4; ++i) acc[mt][i] = fzero;
  for (int ks = 0; ks < 9; ++ks) {
    for (int idx = tid; idx < 32 * 256; idx += 256) {
      int kk = idx >> 8, n = idx & 255;
      int kglob = ks * 32 + kk;
      float v = (kglob < 265) ? W1[((size_t)c * 265 + kglob) * 256 + n] : 0.f;
      *(unsigned short*)(smem + HOFF_B + n * 80 + kk * 2) = f2bf(v);
    }
    __syncthreads();
    bf16x8 bfr[4];
    #pragma unroll
    for (int i = 0; i < 4; ++i)
      bfr[i] = *(const bf16x8*)(smem + HOFF_B + ((w * 4 + i) * 16 + l15) * 80 + kg * 16);
    #pragma unroll
    for (int mt = 0; mt < 2; ++mt) {
      bf16x8 af = *(const bf16x8*)(smem + HOFF_XA + (mt * 16 + l15) * 592 + ks * 64 + kg * 16);
      #pragma unroll
      for (int i = 0; i < 4; ++i)
        acc[mt][i] = __builtin_amdgcn_mfma_f32_16x16x32_bf16(af, bfr[i], acc[mt][i], 0, 0, 0);
    }
    __syncthreads();
  }
  #pragma unroll
  for (int mt = 0; mt < 2; ++mt)
    #pragma unroll
    for (int i = 0; i < 4; ++i) {
      int col = (w * 4 + i) * 16 + l15;
      float bv = *(const float*)(smem + HOFF_B1 + col * 4);
      #pragma unroll
      for (int r = 0; r < 4; ++r) {
        float v = acc[mt][i][r] + bv; v = v > 0.f ? v : 0.f;
        *(unsigned short*)(smem + HOFF_H1 + (mt * 16 + kg * 4 + r) * 528 + col * 2) = f2bf(v);
      }
    }
  __syncthreads();

  // ---- layer 2: h2 = relu(h1 @ W2[c] + b2[c]), K = 256 ----
  #pragma unroll
  for (int mt = 0; mt < 2; ++mt)
    #pragma unroll
    for (int i = 0; i < 4; ++i) acc[mt][i] = fzero;
  for (int ks = 0; ks < 8; ++ks) {
    for (int idx = tid; idx < 32 * 256; idx += 256) {
      int kk = idx >> 8, n = idx & 255;
      float v = W2[((size_t)c * 256 + ks * 32 + kk) * 256 + n];
      *(unsigned short*)(smem + HOFF_B + n * 80 + kk * 2) = f2bf(v);
    }
    __syncthreads();
    bf16x8 bfr[4];
    #pragma unroll
    for (int i = 0; i < 4; ++i)
      bfr[i] = *(const bf16x8*)(smem + HOFF_B + ((w * 4 + i) * 16 + l15) * 80 + kg * 16);
    #pragma unroll
    for (int mt = 0; mt < 2; ++mt) {
      bf16x8 af = *(const bf16x8*)(smem + HOFF_H1 + (mt * 16 + l15) * 528 + ks * 64 + kg * 16);
      #pragma unroll
      for (int i = 0; i < 4; ++i)
        acc[mt][i] = __builtin_amdgcn_mfma_f32_16x16x32_bf16(af, bfr[i], acc[mt][i], 0, 0, 0);
    }
    __syncthreads();
  }
  #pragma unroll
  for (int mt = 0; mt < 2; ++mt)
    #pragma unroll
    for (int i = 0; i < 4; ++i) {
      int col = (w * 4 + i) * 16 + l15;
      float bv = *(const float*)(smem + HOFF_B2 + col * 4);
      #pragma unroll
      for (int r = 0; r < 4; ++r) {
        float v = acc[mt][i][r] + bv; v = v > 0.f ? v : 0.f;
        *(unsigned short*)(smem + HOFF_H2 + (mt * 16 + kg * 4 + r) * 528 + col * 2) = f2bf(v);
      }
    }
  __syncthreads();

  // ---- layer 3: v = h2 @ W3[c] + b3[c] (VALU dot, 4 threads/row) ----
  {
    int row = tid >> 2, q = tid & 3;
    if (row < HROWS) {
      float s = 0.f;
      #pragma unroll
      for (int i = 0; i < 16; ++i) {
        uint2 hh = *(const uint2*)(smem + HOFF_H2 + row * 528 + (q * 64 + i * 4) * 2);
        const float* w3p = (const float*)(smem + HOFF_W3) + q * 64 + i * 4;
        s += bf2f((unsigned short)hh.x)         * w3p[0];
        s += bf2f((unsigned short)(hh.x >> 16)) * w3p[1];
        s += bf2f((unsigned short)hh.y)         * w3p[2];
        s += bf2f((unsigned short)(hh.y >> 16)) * w3p[3];
      }
      s += __shfl_xor(s, 1);
      s += __shfl_xor(s, 2);
      if (q == 0) out[(r0 + row) * 2 + c] = s + b3[c];
    }
  }
}

extern "C" void kernel_launch(void* const* d_in, const int* in_sizes, int n_in,
                              void* d_out, int out_size, void* d_ws, size_t ws_size,
                              hipStream_t stream) {
  const float* particles = (const float*)d_in[0];
  const float* weights   = (const float*)d_in[1];
  const float* action    = (const float*)d_in[2];
  const float* time_idx  = (const float*)d_in[3];
  const float* Wi        = (const float*)d_in[4];
  const float* bi        = (const float*)d_in[5];
  const float* Wh        = (const float*)d_in[6];
  const float* bhn       = (const float*)d_in[7];
  const float* W1        = (const float*)d_in[8];
  const float* b1        = (const float*)d_in[9];
  const float* W2        = (const float*)d_in[10];
  const float* b2        = (const float*)d_in[11];
  const float* W3        = (const float*)d_in[12];
  const float* b3        = (const float*)d_in[13];
  unsigned short* hT = (unsigned short*)d_ws;   // [1024][256] bf16
  float* out = (float*)d_out;

  (void)hipFuncSetAttribute((const void*)gru_kernel,
                            hipFuncAttributeMaxDynamicSharedMemorySize, LDS_GRU);
  (void)hipFuncSetAttribute((const void*)head_kernel,
                            hipFuncAttributeMaxDynamicSharedMemorySize, LDS_HEAD);

  hipLaunchKernelGGL(gru_kernel, dim3(256), dim3(512), LDS_GRU, stream,
                     particles, weights, Wi, bi, Wh, bhn, hT);
  hipLaunchKernelGGL(head_kernel, dim3(64), dim3(256), LDS_HEAD, stream,
                     hT, action, time_idx, W1, b1, W2, b2, W3, b3, out);
}

// Round 9
// 711.994 us; speedup vs baseline: 2.3928x; 1.0191x over previous
//
#include <hip/hip_runtime.h>

// ---------------------------------------------------------------------------
// CriticNetwork: GRU over T=256 steps (B=1024, H=256, F=65) + 2-critic MLP.
// Kernel 1 (gru_kernel): persistent, 256 blocks x 512 thr (8 waves, 2/SIMD).
//   STRUCTURAL FLOOR EVIDENCE (r1-r8): 6 variants land 605-680us regardless
//   of LDS conflicts (3.5e7 vs ~0) -> step is serial-chain bound (barrier ->
//   ds_read -> 8-deep MFMA chains -> gate transcendentals -> barrier) at
//   2 waves/SIMD lockstep. Register wall: whb=384KB/CU fixed; 3 waves/SIMD
//   needs >=174KB of Wh in LDS (>160 cap) -> no higher-occupancy point
//   exists for bf16 Wh. r3 vs r8 isolates bhn-in-LDS as -12us -> registers.
//   Config = r3 skeleton + conflict-free XP layout + bhn in regs:
//   - Wh bf16 B-fragments in regs (whb[6][8], wave w owns N-tiles {w+8j}).
//   - xp LDS layout [j][tt][col][kg]: conflict-free reads AND writes.
//   - fold-after-MFMA (r7's C-init folding spilled; reverted).
//   - plain 8-deep compiler-scheduled ks loop (r4's manual pipeline hurt).
//   - h in a register per lane; fake A-lanes broadcast-read zero row 4.
// Kernel 2 (head_kernel): twin critic MLPs, 64 blocks x 512 thr (staging-
//   bound at 256 thr: 34 barrier phases of load+cvt+ds_write; 512 thr halves
//   per-thread staging and doubles MFMA waves).
// ---------------------------------------------------------------------------

#define TSEQ 256
#define DPDIM 64

typedef float f32x4 __attribute__((ext_vector_type(4)));
typedef __bf16 bf16x8 __attribute__((ext_vector_type(8)));
typedef unsigned short ushort8 __attribute__((ext_vector_type(8)));

static __device__ __forceinline__ unsigned short f2bf(float f) {
  unsigned u = __builtin_bit_cast(unsigned, f);
  return (unsigned short)((u + 0x7fffu + ((u >> 16) & 1u)) >> 16);  // RNE
}
static __device__ __forceinline__ float bf2f(unsigned short h) {
  return __builtin_bit_cast(float, ((unsigned)h) << 16);
}
static __device__ __forceinline__ float sigm(float x) {
  return __builtin_amdgcn_rcpf(1.f + __expf(-x));
}
static __device__ __forceinline__ float tanh_fast(float p) {
  float q = __expf(-2.f * fabsf(p));
  float t = (1.f - q) * __builtin_amdgcn_rcpf(1.f + q);
  return __builtin_bit_cast(float, __builtin_bit_cast(unsigned, t) |
                                   (__builtin_bit_cast(unsigned, p) & 0x80000000u));
}

// ---- GRU kernel LDS layout (bytes) ----
#define OFF_WIT 0         // Wi transposed bf16 [768 n][72 k-stride] = 768*144
#define OFF_XP  110592    // xp bf16 [6 j][4 tt][128 col][4 kg] = 24576
#define OFF_H0  135168    // h buf0 bf16 [4 real rows + 1 zero row][272] stride 544B
#define OFF_H1  137888    // h buf1
#define OFF_BI  140608    // bi f32 [768]
#define OFF_W64 143680    // Wi row 64 (weight channel) f32 [768]
#define LDS_GRU 146752

#define HSTRIDE 544       // h row stride (row bases hit banks {0,8,16,24})

__global__ __launch_bounds__(512, 2) void gru_kernel(
    const float* __restrict__ particles, const float* __restrict__ weights,
    const float* __restrict__ Wi, const float* __restrict__ bi,
    const float* __restrict__ Wh, const float* __restrict__ bhn,
    unsigned short* __restrict__ hT)
{
  extern __shared__ char smem[];
  const int tid  = threadIdx.x;
  const int lane = tid & 63;
  const int w    = tid >> 6;      // wave id 0..7
  const int l15  = lane & 15;
  const int kg   = lane >> 4;     // k-group 0..3
  const int b0   = blockIdx.x * 4;

  // ---------------- prologue ----------------
  for (int idx = tid; idx < 64 * 768; idx += 512) {
    int k = idx / 768, n = idx - k * 768;
    *(unsigned short*)(smem + OFF_WIT + n * 144 + k * 2) = f2bf(Wi[idx]);
  }
  for (int idx = tid; idx < 768; idx += 512) {
    *(float*)(smem + OFF_BI  + idx * 4) = bi[idx];
    *(float*)(smem + OFF_W64 + idx * 4) = Wi[64 * 768 + idx];
  }
  for (int idx = tid; idx < (2 * 5 * HSTRIDE) / 4; idx += 512)
    ((unsigned*)(smem + OFF_H0))[idx] = 0u;   // h0 = 0 (+ shared zero row 4)

  const int hcol0 = w * 16 + l15;       // p=0 col; p=1 col = hcol0+128
  const float bhn0 = bhn[hcol0];        // r3-proven: fits in regs, off the
  const float bhn1 = bhn[hcol0 + 128];  // gate-phase LDS critical path

  // Wh -> register B-fragments. Wave w owns N-tiles {w+8j}, j=0..5:
  //   j=0,1 -> r (cols hcol0, hcol0+128); j=2,3 -> z; j=4,5 -> n.
  bf16x8 whb[6][8];
  #pragma unroll
  for (int j = 0; j < 6; ++j) {
    const int tile = w + 8 * j;
    const float* wp = Wh + (size_t)(kg * 8) * 768 + tile * 16 + l15;
    #pragma unroll
    for (int ks = 0; ks < 8; ++ks) {
      ushort8 tmp;
      #pragma unroll
      for (int e = 0; e < 8; ++e)
        tmp[e] = f2bf(wp[(size_t)(ks * 32 + e) * 768]);
      whb[j][ks] = __builtin_bit_cast(bf16x8, tmp);
    }
  }
  __syncthreads();

  // A-fragment source for the recurrence: M-row l15 is real iff l15%4==0
  // (batch = l15>>2, h row l15>>2); fake lanes read the shared zero row 4
  // (same-address broadcast; ~2-way max conflict).
  const unsigned arow = ((l15 & 3) == 0)
                      ? (unsigned)((l15 >> 2) * HSTRIDE + kg * 16)
                      : (unsigned)(4 * HSTRIDE + kg * 16);

  // xp A-row mapping: row l15 <-> (batch=l15>>2, time=l15&3) => C reg r of
  // lane (l15,kg) = xp(batch=kg, time=t0+r), i.e. writer lane == reader lane.
  const float* pbase = particles +
      ((size_t)(b0 + (l15 >> 2)) * TSEQ + (l15 & 3)) * DPDIM + kg * 8;
  const float* wbase = weights + (size_t)(b0 + kg) * TSEQ;

  // lane's conflict-free XP slot: + j*4096 + tt*1024
  char* const xpb = smem + OFF_XP + hcol0 * 8 + kg * 2;

  f32x4 acc[6];
  const f32x4 fzero = {0.f, 0.f, 0.f, 0.f};
  float hreg0 = 0.f, hreg1 = 0.f;

  for (int g = 0; g < 64; ++g) {
    const int t0 = g * 4;

    // ---------------- xp phase: project inputs for t0..t0+3 ----------------
    #pragma unroll
    for (int j = 0; j < 6; ++j) acc[j] = fzero;
    #pragma unroll
    for (int ks = 0; ks < 2; ++ks) {
      const float* pp = pbase + (size_t)t0 * DPDIM + ks * 32;
      f32x4 pa = *(const f32x4*)pp;
      f32x4 pb = *(const f32x4*)(pp + 4);
      ushort8 tmp;
      tmp[0] = f2bf(pa[0]); tmp[1] = f2bf(pa[1]); tmp[2] = f2bf(pa[2]); tmp[3] = f2bf(pa[3]);
      tmp[4] = f2bf(pb[0]); tmp[5] = f2bf(pb[1]); tmp[6] = f2bf(pb[2]); tmp[7] = f2bf(pb[3]);
      bf16x8 af = __builtin_bit_cast(bf16x8, tmp);
      #pragma unroll
      for (int j = 0; j < 6; ++j) {
        const int n = hcol0 + 128 * j;
        bf16x8 bf = *(const bf16x8*)(smem + OFF_WIT + n * 144 + ks * 64 + kg * 16);
        acc[j] = __builtin_amdgcn_mfma_f32_16x16x32_bf16(af, bf, acc[j], 0, 0, 0);
      }
    }
    // fold bias + weight-channel, park xp in conflict-free LDS slot
    // (writer lane == only reader lane; banks distinct across the wave).
    {
      f32x4 wv = *(const f32x4*)(wbase + t0);
      #pragma unroll
      for (int j = 0; j < 6; ++j) {
        const int col = hcol0 + 128 * j;
        const float biv  = *(const float*)(smem + OFF_BI  + col * 4);
        const float w64v = *(const float*)(smem + OFF_W64 + col * 4);
        #pragma unroll
        for (int r = 0; r < 4; ++r)
          *(unsigned short*)(xpb + j * 4096 + r * 1024) =
              f2bf(acc[j][r] + biv + wv[r] * w64v);
      }
    }

    // ---------------- 4 GRU steps ----------------
    #pragma unroll
    for (int tt = 0; tt < 4; ++tt) {
      const int t     = t0 + tt;
      const int rboff = (t & 1) ? OFF_H1 : OFF_H0;   // read buffer
      const int wboff = (t & 1) ? OFF_H0 : OFF_H1;   // write buffer
      #pragma unroll
      for (int j = 0; j < 6; ++j) acc[j] = fzero;
      const char* hb = smem + rboff;
      #pragma unroll
      for (int ks = 0; ks < 8; ++ks) {
        bf16x8 af = *(const bf16x8*)(hb + arow + ks * 64);
        #pragma unroll
        for (int j = 0; j < 6; ++j)
          acc[j] = __builtin_amdgcn_mfma_f32_16x16x32_bf16(af, whb[j][ks], acc[j], 0, 0, 0);
      }
      // Gates (reg 0 = batch kg): xp from conflict-free LDS; bhn/h in regs.
      float xr0 = bf2f(*(const unsigned short*)(xpb + 0 * 4096 + tt * 1024));
      float xr1 = bf2f(*(const unsigned short*)(xpb + 1 * 4096 + tt * 1024));
      float xz0 = bf2f(*(const unsigned short*)(xpb + 2 * 4096 + tt * 1024));
      float xz1 = bf2f(*(const unsigned short*)(xpb + 3 * 4096 + tt * 1024));
      float xn0 = bf2f(*(const unsigned short*)(xpb + 4 * 4096 + tt * 1024));
      float xn1 = bf2f(*(const unsigned short*)(xpb + 5 * 4096 + tt * 1024));
      float rr0 = sigm(xr0 + acc[0][0]);
      float zz0 = sigm(xz0 + acc[2][0]);
      float nn0 = tanh_fast(xn0 + rr0 * (acc[4][0] + bhn0));
      unsigned short h0u = f2bf(nn0 + zz0 * (hreg0 - nn0));
      hreg0 = bf2f(h0u);
      float rr1 = sigm(xr1 + acc[1][0]);
      float zz1 = sigm(xz1 + acc[3][0]);
      float nn1 = tanh_fast(xn1 + rr1 * (acc[5][0] + bhn1));
      unsigned short h1u = f2bf(nn1 + zz1 * (hreg1 - nn1));
      hreg1 = bf2f(h1u);
      *(unsigned short*)(smem + wboff + kg * HSTRIDE + hcol0 * 2)         = h0u;
      *(unsigned short*)(smem + wboff + kg * HSTRIDE + (hcol0 + 128) * 2) = h1u;
      __syncthreads();
    }
  }

  // epilogue: final h lives in registers -> store directly
  hT[(size_t)(b0 + kg) * 256 + hcol0]       = f2bf(hreg0);
  hT[(size_t)(b0 + kg) * 256 + hcol0 + 128] = f2bf(hreg1);
}

// ---- Head kernel LDS layout ----
#define HOFF_XA 0         // x tile bf16 [32][296] stride 592B
#define HOFF_B  37888     // B stage bf16 [256 n][40 k] stride 80B
#define HOFF_H1 58368     // h1 bf16 [32][264] stride 528B
#define HOFF_H2 92160
#define HOFF_B1 125952
#define HOFF_B2 126976
#define HOFF_W3 128000
#define LDS_HEAD 129024

#define HROWS 32          // rows per head block (64 blocks = 32 rows x 2 critics)

__global__ __launch_bounds__(512) void head_kernel(
    const unsigned short* __restrict__ hT, const float* __restrict__ action,
    const float* __restrict__ time_idx, const float* __restrict__ W1,
    const float* __restrict__ b1, const float* __restrict__ W2,
    const float* __restrict__ b2, const float* __restrict__ W3,
    const float* __restrict__ b3, float* __restrict__ out)
{
  extern __shared__ char smem[];
  const int tid  = threadIdx.x;
  const int lane = tid & 63;
  const int w    = tid >> 6;      // wave 0..7; wave w owns N-tiles {2w, 2w+1}
  const int l15  = lane & 15;
  const int kg   = lane >> 4;
  const int c    = blockIdx.x & 1;
  const int rt   = blockIdx.x >> 1;
  const int r0   = rt * HROWS;

  if (tid < 256) {
    *(float*)(smem + HOFF_B1 + tid * 4) = b1[c * 256 + tid];
    *(float*)(smem + HOFF_B2 + tid * 4) = b2[c * 256 + tid];
    *(float*)(smem + HOFF_W3 + tid * 4) = W3[c * 256 + tid];
  }
  // x = [h | action | t/100 | zero-pad to 288]
  for (int idx = tid; idx < HROWS * 296; idx += 512) {
    int row = idx / 296, k = idx - row * 296;
    unsigned short v;
    if (k < 256)       v = hT[(r0 + row) * 256 + k];
    else if (k < 264)  v = f2bf(action[(r0 + row) * 8 + (k - 256)]);
    else if (k == 264) v = f2bf(time_idx[r0 + row] * 0.01f);
    else               v = 0;
    *(unsigned short*)(smem + HOFF_XA + row * 592 + k * 2) = v;
  }

  f32x4 acc[2][2];
  const f32x4 fzero = {0.f, 0.f, 0.f, 0.f};

  // ---- layer 1: h1 = relu(x @ W1[c] + b1[c]), K = 265 padded to 288 ----
  #pragma unroll
  for (int mt = 0; mt < 2; ++mt)
    #pragma unroll
    for (int i = 0; i < 2; ++i) acc[mt][i] = fzero;
  for (int ks = 0; ks < 9; ++ks) {
    for (int idx = tid; idx < 32 * 256; idx += 512) {
      int kk = idx >> 8, n = idx & 255;
      int kglob = ks * 32 + kk;
      float v = (kglob < 265) ? W1[((size_t)c * 265 + kglob) * 256 + n] : 0.f;
      *(unsigned short*)(smem + HOFF_B + n * 80 + kk * 2) = f2bf(v);
    }
    __syncthreads();
    bf16x8 bfr[2];
    #pragma unroll
    for (int i = 0; i < 2; ++i)
      bfr[i] = *(const bf16x8*)(smem + HOFF_B + ((w * 2 + i) * 16 + l15) * 80 + kg * 16);
    #pragma unroll
    for (int mt = 0; mt < 2; ++mt) {
      bf16x8 af = *(const bf16x8*)(smem + HOFF_XA + (mt * 16 + l15) * 592 + ks * 64 + kg * 16);
      #pragma unroll
      for (int i = 0; i < 2; ++i)
        acc[mt][i] = __builtin_amdgcn_mfma_f32_16x16x32_bf16(af, bfr[i], acc[mt][i], 0, 0, 0);
    }
    __syncthreads();
  }
  #pragma unroll
  for (int mt = 0; mt < 2; ++mt)
    #pragma unroll
    for (int i = 0; i < 2; ++i) {
      int col = (w * 2 + i) * 16 + l15;
      float bv = *(const float*)(smem + HOFF_B1 + col * 4);
      #pragma unroll
      for (int r = 0; r < 4; ++r) {
        float v = acc[mt][i][r] + bv; v = v > 0.f ? v : 0.f;
        *(unsigned short*)(smem + HOFF_H1 + (mt * 16 + kg * 4 + r) * 528 + col * 2) = f2bf(v);
      }
    }
  __syncthreads();

  // ---- layer 2: h2 = relu(h1 @ W2[c] + b2[c]), K = 256 ----
  #pragma unroll
  for (int mt = 0; mt < 2; ++mt)
    #pragma unroll
    for (int i = 0; i < 2; ++i) acc[mt][i] = fzero;
  for (int ks = 0; ks < 8; ++ks) {
    for (int idx = tid; idx < 32 * 256; idx += 512) {
      int kk = idx >> 8, n = idx & 255;
      float v = W2[((size_t)c * 256 + ks * 32 + kk) * 256 + n];
      *(unsigned short*)(smem + HOFF_B + n * 80 + kk * 2) = f2bf(v);
    }
    __syncthreads();
    bf16x8 bfr[2];
    #pragma unroll
    for (int i = 0; i < 2; ++i)
      bfr[i] = *(const bf16x8*)(smem + HOFF_B + ((w * 2 + i) * 16 + l15) * 80 + kg * 16);
    #pragma unroll
    for (int mt = 0; mt < 2; ++mt) {
      bf16x8 af = *(const bf16x8*)(smem + HOFF_H1 + (mt * 16 + l15) * 528 + ks * 64 + kg * 16);
      #pragma unroll
      for (int i = 0; i < 2; ++i)
        acc[mt][i] = __builtin_amdgcn_mfma_f32_16x16x32_bf16(af, bfr[i], acc[mt][i], 0, 0, 0);
    }
    __syncthreads();
  }
  #pragma unroll
  for (int mt = 0; mt < 2; ++mt)
    #pragma unroll
    for (int i = 0; i < 2; ++i) {
      int col = (w * 2 + i) * 16 + l15;
      float bv = *(const float*)(smem + HOFF_B2 + col * 4);
      #pragma unroll
      for (int r = 0; r < 4; ++r) {
        float v = acc[mt][i][r] + bv; v = v > 0.f ? v : 0.f;
        *(unsigned short*)(smem + HOFF_H2 + (mt * 16 + kg * 4 + r) * 528 + col * 2) = f2bf(v);
      }
    }
  __syncthreads();

  // ---- layer 3: v = h2 @ W3[c] + b3[c] (VALU dot, 4 threads/row) ----
  {
    int row = tid >> 2, q = tid & 3;
    if (row < HROWS) {
      float s = 0.f;
      #pragma unroll
      for (int i = 0; i < 16; ++i) {
        uint2 hh = *(const uint2*)(smem + HOFF_H2 + row * 528 + (q * 64 + i * 4) * 2);
        const float* w3p = (const float*)(smem + HOFF_W3) + q * 64 + i * 4;
        s += bf2f((unsigned short)hh.x)         * w3p[0];
        s += bf2f((unsigned short)(hh.x >> 16)) * w3p[1];
        s += bf2f((unsigned short)hh.y)         * w3p[2];
        s += bf2f((unsigned short)(hh.y >> 16)) * w3p[3];
      }
      s += __shfl_xor(s, 1);
      s += __shfl_xor(s, 2);
      if (q == 0) out[(r0 + row) * 2 + c] = s + b3[c];
    }
  }
}

extern "C" void kernel_launch(void* const* d_in, const int* in_sizes, int n_in,
                              void* d_out, int out_size, void* d_ws, size_t ws_size,
                              hipStream_t stream) {
  const float* particles = (const float*)d_in[0];
  const float* weights   = (const float*)d_in[1];
  const float* action    = (const float*)d_in[2];
  const float* time_idx  = (const float*)d_in[3];
  const float* Wi        = (const float*)d_in[4];
  const float* bi        = (const float*)d_in[5];
  const float* Wh        = (const float*)d_in[6];
  const float* bhn       = (const float*)d_in[7];
  const float* W1        = (const float*)d_in[8];
  const float* b1        = (const float*)d_in[9];
  const float* W2        = (const float*)d_in[10];
  const float* b2        = (const float*)d_in[11];
  const float* W3        = (const float*)d_in[12];
  const float* b3        = (const float*)d_in[13];
  unsigned short* hT = (unsigned short*)d_ws;   // [1024][256] bf16
  float* out = (float*)d_out;

  (void)hipFuncSetAttribute((const void*)gru_kernel,
                            hipFuncAttributeMaxDynamicSharedMemorySize, LDS_GRU);
  (void)hipFuncSetAttribute((const void*)head_kernel,
                            hipFuncAttributeMaxDynamicSharedMemorySize, LDS_HEAD);

  hipLaunchKernelGGL(gru_kernel, dim3(256), dim3(512), LDS_GRU, stream,
                     particles, weights, Wi, bi, Wh, bhn, hT);
  hipLaunchKernelGGL(head_kernel, dim3(64), dim3(512), LDS_HEAD, stream,
                     hT, action, time_idx, W1, b1, W2, b2, W3, b3, out);
}